// Round 3
// baseline (1000.149 us; speedup 1.0000x reference)
//
#include <hip/hip_runtime.h>

#define NN 50000
#define NE 600000
#define NP 100000
#define DD 128

// ---------------- CSR build ----------------

__global__ __launch_bounds__(256) void k_count(const int* __restrict__ dst, int* __restrict__ deg) {
    int i = blockIdx.x * 256 + threadIdx.x;
    if (i < NE) atomicAdd(&deg[dst[i]], 1);
}

__global__ __launch_bounds__(1024) void k_scan1(const int* __restrict__ deg, int* __restrict__ excl,
                                                int* __restrict__ sums) {
    __shared__ int tmp[1024];
    int t = threadIdx.x;
    int gid = blockIdx.x * 1024 + t;
    int v = (gid < NN) ? deg[gid] : 0;
    tmp[t] = v;
    __syncthreads();
    #pragma unroll
    for (int off = 1; off < 1024; off <<= 1) {
        int u = (t >= off) ? tmp[t - off] : 0;
        __syncthreads();
        tmp[t] += u;
        __syncthreads();
    }
    excl[gid] = tmp[t] - v;                 // exclusive within block
    if (t == 1023) sums[blockIdx.x] = tmp[t];
}

__global__ __launch_bounds__(64) void k_scan2(int* __restrict__ sums) {
    int t = threadIdx.x;                    // one wave
    int v = (t < 49) ? sums[t] : 0;
    int orig = v;
    #pragma unroll
    for (int off = 1; off < 64; off <<= 1) {
        int u = __shfl_up(v, off, 64);
        if (t >= off) v += u;
    }
    if (t < 64) sums[t] = v - orig;         // exclusive
}

__global__ __launch_bounds__(256) void k_scan3(int* __restrict__ row_ptr, const int* __restrict__ sums,
                                               const int* __restrict__ deg, float* __restrict__ inv_deg) {
    int i = blockIdx.x * 256 + threadIdx.x;
    if (i < NN) {
        row_ptr[i] += sums[i >> 10];
        int d = deg[i];
        inv_deg[i] = 1.0f / (float)(d > 1 ? d : 1);
        if (i == 0) row_ptr[NN] = NE;
    }
}

__global__ __launch_bounds__(256) void k_fill(const int* __restrict__ src, const int* __restrict__ dst,
                                              const int* __restrict__ row_ptr, int* __restrict__ cursor,
                                              int* __restrict__ csr) {
    int i = blockIdx.x * 256 + threadIdx.x;
    if (i < NE) {
        int d = dst[i];
        int p = row_ptr[d] + atomicAdd(&cursor[d], 1);
        csr[p] = src[i];
    }
}

// ---------------- mean aggregation: one wave per node, float4 x 2 rows/iter ----------------

__global__ __launch_bounds__(256) void k_agg(const float* __restrict__ h, const int* __restrict__ row_ptr,
                                             const int* __restrict__ csr, const float* __restrict__ inv_deg,
                                             float* __restrict__ agg) {
    int wid = (int)((blockIdx.x * 256 + threadIdx.x) >> 6);
    int lane = threadIdx.x & 63;
    if (wid >= NN) return;
    int beg = row_ptr[wid], end = row_ptr[wid + 1];
    int half = lane >> 5, q = lane & 31;     // lanes 0-31: even edge, 32-63: odd edge
    float4 s = {0.f, 0.f, 0.f, 0.f};
    int i = beg;
    for (; i + 4 <= end; i += 4) {           // 2 independent row-loads in flight
        int s0 = csr[i + half], s1 = csr[i + 2 + half];
        float4 v0 = ((const float4*)(h + (size_t)s0 * DD))[q];
        float4 v1 = ((const float4*)(h + (size_t)s1 * DD))[q];
        s.x += v0.x + v1.x; s.y += v0.y + v1.y; s.z += v0.z + v1.z; s.w += v0.w + v1.w;
    }
    for (; i + half < end; i += 2) {
        int s0 = csr[i + half];
        float4 v = ((const float4*)(h + (size_t)s0 * DD))[q];
        s.x += v.x; s.y += v.y; s.z += v.z; s.w += v.w;
    }
    s.x += __shfl_xor(s.x, 32, 64);
    s.y += __shfl_xor(s.y, 32, 64);
    s.z += __shfl_xor(s.z, 32, 64);
    s.w += __shfl_xor(s.w, 32, 64);
    if (half == 0) {
        float sc = inv_deg[wid];
        float4 o = {s.x * sc, s.y * sc, s.z * sc, s.w * sc};
        ((float4*)(agg + (size_t)wid * DD))[q] = o;
    }
}

// ---------------- SAGE layer: hout = relu?(hin@Ws + agg@Wn + b) ----------------
// LDS-free: each thread owns 4 rows x 8 cols; k-broadcast via __shfl from the
// 16 c-lanes of its wave quarter. No barriers, no bank conflicts.

template <int RELU>
__global__ __launch_bounds__(256) void k_layer(const float* __restrict__ hin, const float* __restrict__ agg,
                                               const float* __restrict__ Ws, const float* __restrict__ Wn,
                                               const float* __restrict__ bias, float* __restrict__ hout) {
    int t = threadIdx.x;
    int lane = t & 63;
    int g = t >> 4;                          // 0..15: rows 4g..4g+3
    int c = t & 15;                          // cols 8c..8c+7
    int row0 = blockIdx.x * 64;
    float hreg[4][8], areg[4][8];
    #pragma unroll
    for (int i = 0; i < 4; ++i) {
        int row = row0 + 4 * g + i;
        float4 h0 = {0,0,0,0}, h1 = {0,0,0,0}, a0 = {0,0,0,0}, a1 = {0,0,0,0};
        if (row < NN) {
            const float4* hp = (const float4*)(hin + (size_t)row * DD);
            const float4* ap = (const float4*)(agg + (size_t)row * DD);
            h0 = hp[2 * c]; h1 = hp[2 * c + 1];
            a0 = ap[2 * c]; a1 = ap[2 * c + 1];
        }
        hreg[i][0] = h0.x; hreg[i][1] = h0.y; hreg[i][2] = h0.z; hreg[i][3] = h0.w;
        hreg[i][4] = h1.x; hreg[i][5] = h1.y; hreg[i][6] = h1.z; hreg[i][7] = h1.w;
        areg[i][0] = a0.x; areg[i][1] = a0.y; areg[i][2] = a0.z; areg[i][3] = a0.w;
        areg[i][4] = a1.x; areg[i][5] = a1.y; areg[i][6] = a1.z; areg[i][7] = a1.w;
    }
    float acc[4][8];
    #pragma unroll
    for (int i = 0; i < 4; ++i)
        #pragma unroll
        for (int j = 0; j < 8; ++j) acc[i][j] = 0.f;
    const float4* wsp = (const float4*)Ws;
    const float4* wnp = (const float4*)Wn;
    #pragma unroll 2
    for (int cs = 0; cs < 16; ++cs) {
        int sl = (lane & 48) | cs;
        #pragma unroll
        for (int jj = 0; jj < 8; ++jj) {
            float h0 = __shfl(hreg[0][jj], sl, 64);
            float h1 = __shfl(hreg[1][jj], sl, 64);
            float h2 = __shfl(hreg[2][jj], sl, 64);
            float h3 = __shfl(hreg[3][jj], sl, 64);
            float a0 = __shfl(areg[0][jj], sl, 64);
            float a1 = __shfl(areg[1][jj], sl, 64);
            float a2 = __shfl(areg[2][jj], sl, 64);
            float a3 = __shfl(areg[3][jj], sl, 64);
            int k = 8 * cs + jj;
            float4 ws0 = wsp[k * 32 + 2 * c], ws1 = wsp[k * 32 + 2 * c + 1];
            float4 wn0 = wnp[k * 32 + 2 * c], wn1 = wnp[k * 32 + 2 * c + 1];
            float hv[4] = {h0, h1, h2, h3};
            float av[4] = {a0, a1, a2, a3};
            float wv[8] = {ws0.x, ws0.y, ws0.z, ws0.w, ws1.x, ws1.y, ws1.z, ws1.w};
            float uv[8] = {wn0.x, wn0.y, wn0.z, wn0.w, wn1.x, wn1.y, wn1.z, wn1.w};
            #pragma unroll
            for (int i = 0; i < 4; ++i)
                #pragma unroll
                for (int j = 0; j < 8; ++j)
                    acc[i][j] = fmaf(hv[i], wv[j], fmaf(av[i], uv[j], acc[i][j]));
        }
    }
    float4 b0 = ((const float4*)bias)[2 * c], b1 = ((const float4*)bias)[2 * c + 1];
    float bv[8] = {b0.x, b0.y, b0.z, b0.w, b1.x, b1.y, b1.z, b1.w};
    #pragma unroll
    for (int i = 0; i < 4; ++i) {
        int row = row0 + 4 * g + i;
        if (row < NN) {
            float o[8];
            #pragma unroll
            for (int j = 0; j < 8; ++j) {
                float v = acc[i][j] + bv[j];
                if (RELU) v = fmaxf(v, 0.f);
                o[j] = v;
            }
            float4 s0 = {o[0], o[1], o[2], o[3]}, s1 = {o[4], o[5], o[6], o[7]};
            ((float4*)hout)[(size_t)row * 32 + 2 * c] = s0;
            ((float4*)hout)[(size_t)row * 32 + 2 * c + 1] = s1;
        }
    }
}

// ---------------- fused predictor (LDS-free, shfl k-broadcast) ----------------

__global__ __launch_bounds__(256) void k_pred(const float* __restrict__ h,
                                              const int* __restrict__ ps, const int* __restrict__ pd,
                                              const int* __restrict__ ns, const int* __restrict__ nd,
                                              const float* __restrict__ Wp1, const float* __restrict__ bp1,
                                              const float* __restrict__ Wp2, const float* __restrict__ bp2,
                                              const float* __restrict__ Wp3, const float* __restrict__ bp3,
                                              float* __restrict__ out) {
    int t = threadIdx.x;
    int lane = t & 63;
    int g = t >> 4;
    int c = t & 15;
    int row0 = blockIdx.x * 64;
    float e[4][8];
    #pragma unroll
    for (int i = 0; i < 4; ++i) {
        int row = row0 + 4 * g + i;
        int s, d;
        if (row < NP) { s = ps[row]; d = pd[row]; }
        else          { s = ns[row - NP]; d = nd[row - NP]; }
        const float4* hs = (const float4*)(h + (size_t)s * DD);
        const float4* hd = (const float4*)(h + (size_t)d * DD);
        float4 a0 = hs[2 * c], a1 = hs[2 * c + 1];
        float4 b0 = hd[2 * c], b1 = hd[2 * c + 1];
        e[i][0] = a0.x * b0.x; e[i][1] = a0.y * b0.y; e[i][2] = a0.z * b0.z; e[i][3] = a0.w * b0.w;
        e[i][4] = a1.x * b1.x; e[i][5] = a1.y * b1.y; e[i][6] = a1.z * b1.z; e[i][7] = a1.w * b1.w;
    }
    float acc[4][8];
    #pragma unroll
    for (int i = 0; i < 4; ++i)
        #pragma unroll
        for (int j = 0; j < 8; ++j) acc[i][j] = 0.f;
    // GEMM1: acc = e @ Wp1
    const float4* w1p = (const float4*)Wp1;
    #pragma unroll 2
    for (int cs = 0; cs < 16; ++cs) {
        int sl = (lane & 48) | cs;
        #pragma unroll
        for (int jj = 0; jj < 8; ++jj) {
            float e0 = __shfl(e[0][jj], sl, 64);
            float e1 = __shfl(e[1][jj], sl, 64);
            float e2 = __shfl(e[2][jj], sl, 64);
            float e3 = __shfl(e[3][jj], sl, 64);
            int k = 8 * cs + jj;
            float4 w0 = w1p[k * 32 + 2 * c], w1 = w1p[k * 32 + 2 * c + 1];
            float ev[4] = {e0, e1, e2, e3};
            float wv[8] = {w0.x, w0.y, w0.z, w0.w, w1.x, w1.y, w1.z, w1.w};
            #pragma unroll
            for (int i = 0; i < 4; ++i)
                #pragma unroll
                for (int j = 0; j < 8; ++j)
                    acc[i][j] = fmaf(ev[i], wv[j], acc[i][j]);
        }
    }
    // z1 = relu(acc + bp1) -> reuse e; reset acc
    {
        float4 b0 = ((const float4*)bp1)[2 * c], b1 = ((const float4*)bp1)[2 * c + 1];
        float bv[8] = {b0.x, b0.y, b0.z, b0.w, b1.x, b1.y, b1.z, b1.w};
        #pragma unroll
        for (int i = 0; i < 4; ++i)
            #pragma unroll
            for (int j = 0; j < 8; ++j) {
                e[i][j] = fmaxf(acc[i][j] + bv[j], 0.f);
                acc[i][j] = 0.f;
            }
    }
    // GEMM2: acc = z1 @ Wp2
    const float4* w2p = (const float4*)Wp2;
    #pragma unroll 2
    for (int cs = 0; cs < 16; ++cs) {
        int sl = (lane & 48) | cs;
        #pragma unroll
        for (int jj = 0; jj < 8; ++jj) {
            float e0 = __shfl(e[0][jj], sl, 64);
            float e1 = __shfl(e[1][jj], sl, 64);
            float e2 = __shfl(e[2][jj], sl, 64);
            float e3 = __shfl(e[3][jj], sl, 64);
            int k = 8 * cs + jj;
            float4 w0 = w2p[k * 32 + 2 * c], w1 = w2p[k * 32 + 2 * c + 1];
            float ev[4] = {e0, e1, e2, e3};
            float wv[8] = {w0.x, w0.y, w0.z, w0.w, w1.x, w1.y, w1.z, w1.w};
            #pragma unroll
            for (int i = 0; i < 4; ++i)
                #pragma unroll
                for (int j = 0; j < 8; ++j)
                    acc[i][j] = fmaf(ev[i], wv[j], acc[i][j]);
        }
    }
    // z2 = relu(acc + bp2); dot with Wp3 cols 8c..8c+7; reduce over the 16 c-lanes
    float4 c0 = ((const float4*)bp2)[2 * c], c1 = ((const float4*)bp2)[2 * c + 1];
    float cv[8] = {c0.x, c0.y, c0.z, c0.w, c1.x, c1.y, c1.z, c1.w};
    float4 w30 = ((const float4*)Wp3)[2 * c], w31 = ((const float4*)Wp3)[2 * c + 1];
    float w3v[8] = {w30.x, w30.y, w30.z, w30.w, w31.x, w31.y, w31.z, w31.w};
    float p[4] = {0.f, 0.f, 0.f, 0.f};
    #pragma unroll
    for (int i = 0; i < 4; ++i)
        #pragma unroll
        for (int j = 0; j < 8; ++j)
            p[i] = fmaf(fmaxf(acc[i][j] + cv[j], 0.f), w3v[j], p[i]);
    #pragma unroll
    for (int off = 1; off < 16; off <<= 1) {
        #pragma unroll
        for (int i = 0; i < 4; ++i) p[i] += __shfl_xor(p[i], off, 64);
    }
    if (c == 0) {
        float bb = bp3[0];
        #pragma unroll
        for (int i = 0; i < 4; ++i) out[row0 + 4 * g + i] = p[i] + bb;
    }
}

// ---------------- launch ----------------

extern "C" void kernel_launch(void* const* d_in, const int* in_sizes, int n_in,
                              void* d_out, int out_size, void* d_ws, size_t ws_size,
                              hipStream_t stream) {
    const float* x      = (const float*)d_in[0];
    const float* W_self = (const float*)d_in[1];
    const float* W_neigh= (const float*)d_in[2];
    const float* b      = (const float*)d_in[3];
    const float* Wp1    = (const float*)d_in[4];
    const float* bp1    = (const float*)d_in[5];
    const float* Wp2    = (const float*)d_in[6];
    const float* bp2    = (const float*)d_in[7];
    const float* Wp3    = (const float*)d_in[8];
    const float* bp3    = (const float*)d_in[9];
    const int* edge_src = (const int*)d_in[10];
    const int* edge_dst = (const int*)d_in[11];
    const int* pos_src  = (const int*)d_in[12];
    const int* pos_dst  = (const int*)d_in[13];
    const int* neg_src  = (const int*)d_in[14];
    const int* neg_dst  = (const int*)d_in[15];
    float* out = (float*)d_out;

    size_t o = 0;
    char* base = (char*)d_ws;
    auto take = [&](size_t bytes) -> void* {
        void* r = base + o;
        o = (o + bytes + 255) & ~(size_t)255;
        return r;
    };
    int*   deg     = (int*)take(NN * 4);
    int*   cursor  = (int*)take(NN * 4);
    int*   row_ptr = (int*)take(50304 * 4);   // scan1 writes up to 50175; [NN]=50000 used
    int*   sums    = (int*)take(64 * 4);
    int*   csr     = (int*)take(NE * 4);
    float* inv_deg = (float*)take(NN * 4);
    float* aggm    = (float*)take((size_t)NN * DD * 4);
    float* hA      = (float*)take((size_t)NN * DD * 4);
    float* hB      = (float*)take((size_t)NN * DD * 4);
    (void)ws_size; (void)n_in; (void)in_sizes; (void)out_size;

    hipMemsetAsync(deg, 0, NN * 4, stream);
    hipMemsetAsync(cursor, 0, NN * 4, stream);

    k_count<<<(NE + 255) / 256, 256, 0, stream>>>(edge_dst, deg);
    k_scan1<<<49, 1024, 0, stream>>>(deg, row_ptr, sums);
    k_scan2<<<1, 64, 0, stream>>>(sums);
    k_scan3<<<(NN + 255) / 256, 256, 0, stream>>>(row_ptr, sums, deg, inv_deg);
    k_fill<<<(NE + 255) / 256, 256, 0, stream>>>(edge_src, edge_dst, row_ptr, cursor, csr);

    const int aggGrid = (NN + 3) / 4;          // 4 waves/block, wave per node
    const int layGrid = (NN + 63) / 64;        // 64 rows/block

    // layer 0: x -> hA
    k_agg<<<aggGrid, 256, 0, stream>>>(x, row_ptr, csr, inv_deg, aggm);
    k_layer<1><<<layGrid, 256, 0, stream>>>(x, aggm, W_self, W_neigh, b, hA);
    // layer 1: hA -> hB
    k_agg<<<aggGrid, 256, 0, stream>>>(hA, row_ptr, csr, inv_deg, aggm);
    k_layer<1><<<layGrid, 256, 0, stream>>>(hA, aggm, W_self + 16384, W_neigh + 16384, b + 128, hB);
    // layer 2 (no relu): hB -> hA
    k_agg<<<aggGrid, 256, 0, stream>>>(hB, row_ptr, csr, inv_deg, aggm);
    k_layer<0><<<layGrid, 256, 0, stream>>>(hB, aggm, W_self + 32768, W_neigh + 32768, b + 256, hA);

    k_pred<<<(2 * NP) / 64, 256, 0, stream>>>(hA, pos_src, pos_dst, neg_src, neg_dst,
                                              Wp1, bp1, Wp2, bp2, Wp3, bp3, out);
}

// Round 5
// 774.599 us; speedup vs baseline: 1.2912x; 1.2912x over previous
//
#include <hip/hip_runtime.h>

#define NN 50000
#define NE 600000
#define NP 100000
#define DD 128

// ---------------- CSR build ----------------

__global__ __launch_bounds__(256) void k_count(const int* __restrict__ dst, int* __restrict__ deg) {
    int i = blockIdx.x * 256 + threadIdx.x;
    if (i < NE) atomicAdd(&deg[dst[i]], 1);
}

__global__ __launch_bounds__(1024) void k_scan1(const int* __restrict__ deg, int* __restrict__ excl,
                                                int* __restrict__ sums) {
    __shared__ int tmp[1024];
    int t = threadIdx.x;
    int gid = blockIdx.x * 1024 + t;
    int v = (gid < NN) ? deg[gid] : 0;
    tmp[t] = v;
    __syncthreads();
    #pragma unroll
    for (int off = 1; off < 1024; off <<= 1) {
        int u = (t >= off) ? tmp[t - off] : 0;
        __syncthreads();
        tmp[t] += u;
        __syncthreads();
    }
    excl[gid] = tmp[t] - v;                 // exclusive within block
    if (t == 1023) sums[blockIdx.x] = tmp[t];
}

__global__ __launch_bounds__(64) void k_scan2(int* __restrict__ sums) {
    int t = threadIdx.x;                    // one wave
    int v = (t < 49) ? sums[t] : 0;
    int orig = v;
    #pragma unroll
    for (int off = 1; off < 64; off <<= 1) {
        int u = __shfl_up(v, off, 64);
        if (t >= off) v += u;
    }
    if (t < 64) sums[t] = v - orig;         // exclusive
}

__global__ __launch_bounds__(256) void k_scan3(int* __restrict__ row_ptr, const int* __restrict__ sums,
                                               const int* __restrict__ deg, float* __restrict__ inv_deg) {
    int i = blockIdx.x * 256 + threadIdx.x;
    if (i < NN) {
        row_ptr[i] += sums[i >> 10];
        int d = deg[i];
        inv_deg[i] = 1.0f / (float)(d > 1 ? d : 1);
        if (i == 0) row_ptr[NN] = NE;
    }
}

__global__ __launch_bounds__(256) void k_fill(const int* __restrict__ src, const int* __restrict__ dst,
                                              const int* __restrict__ row_ptr, int* __restrict__ cursor,
                                              int* __restrict__ csr) {
    int i = blockIdx.x * 256 + threadIdx.x;
    if (i < NE) {
        int d = dst[i];
        int p = row_ptr[d] + atomicAdd(&cursor[d], 1);
        csr[p] = src[i];
    }
}

// ---------------- mean aggregation: one wave per node, float4 x 2 rows/iter ----------------

__global__ __launch_bounds__(256) void k_agg(const float* __restrict__ h, const int* __restrict__ row_ptr,
                                             const int* __restrict__ csr, const float* __restrict__ inv_deg,
                                             float* __restrict__ agg) {
    int wid = (int)((blockIdx.x * 256 + threadIdx.x) >> 6);
    int lane = threadIdx.x & 63;
    if (wid >= NN) return;
    int beg = row_ptr[wid], end = row_ptr[wid + 1];
    int half = lane >> 5, q = lane & 31;     // lanes 0-31: even edge, 32-63: odd edge
    float4 s = {0.f, 0.f, 0.f, 0.f};
    int i = beg;
    for (; i + 4 <= end; i += 4) {           // 2 independent row-loads in flight
        int s0 = csr[i + half], s1 = csr[i + 2 + half];
        float4 v0 = ((const float4*)(h + (size_t)s0 * DD))[q];
        float4 v1 = ((const float4*)(h + (size_t)s1 * DD))[q];
        s.x += v0.x + v1.x; s.y += v0.y + v1.y; s.z += v0.z + v1.z; s.w += v0.w + v1.w;
    }
    for (; i + half < end; i += 2) {
        int s0 = csr[i + half];
        float4 v = ((const float4*)(h + (size_t)s0 * DD))[q];
        s.x += v.x; s.y += v.y; s.z += v.z; s.w += v.w;
    }
    s.x += __shfl_xor(s.x, 32, 64);
    s.y += __shfl_xor(s.y, 32, 64);
    s.z += __shfl_xor(s.z, 32, 64);
    s.w += __shfl_xor(s.w, 32, 64);
    if (half == 0) {
        float sc = inv_deg[wid];
        float4 o = {s.x * sc, s.y * sc, s.z * sc, s.w * sc};
        ((float4*)(agg + (size_t)wid * DD))[q] = o;
    }
}

// ---------------- SAGE layer: hout = relu?(hin@Ws + agg@Wn + b) ----------------
// Activations in registers (shfl k-broadcast); weights staged in LDS in BK=32
// chunks so each W element is read once per block from L2 (not per-thread).
// Thread tile: 4 rows x 8 cols. Per k: 8 bpermute + 4 ds_read_b128 + 64 FMA.

template <int RELU>
__global__ __launch_bounds__(256) void k_layer(const float* __restrict__ hin, const float* __restrict__ agg,
                                               const float* __restrict__ Ws, const float* __restrict__ Wn,
                                               const float* __restrict__ bias, float* __restrict__ hout) {
    __shared__ float4 wsBuf[1024];           // 32 x 128 floats = 16 KB
    __shared__ float4 wnBuf[1024];
    int t = threadIdx.x;
    int lane = t & 63;
    int g = t >> 4;                          // 0..15: rows 4g..4g+3
    int c = t & 15;                          // cols 8c..8c+7
    int row0 = blockIdx.x * 64;
    float hreg[4][8], areg[4][8];
    #pragma unroll
    for (int i = 0; i < 4; ++i) {
        int row = row0 + 4 * g + i;
        float4 h0 = {0,0,0,0}, h1 = {0,0,0,0}, a0 = {0,0,0,0}, a1 = {0,0,0,0};
        if (row < NN) {
            const float4* hp = (const float4*)(hin + (size_t)row * DD);
            const float4* ap = (const float4*)(agg + (size_t)row * DD);
            h0 = hp[2 * c]; h1 = hp[2 * c + 1];
            a0 = ap[2 * c]; a1 = ap[2 * c + 1];
        }
        hreg[i][0] = h0.x; hreg[i][1] = h0.y; hreg[i][2] = h0.z; hreg[i][3] = h0.w;
        hreg[i][4] = h1.x; hreg[i][5] = h1.y; hreg[i][6] = h1.z; hreg[i][7] = h1.w;
        areg[i][0] = a0.x; areg[i][1] = a0.y; areg[i][2] = a0.z; areg[i][3] = a0.w;
        areg[i][4] = a1.x; areg[i][5] = a1.y; areg[i][6] = a1.z; areg[i][7] = a1.w;
    }
    float acc[4][8];
    #pragma unroll
    for (int i = 0; i < 4; ++i)
        #pragma unroll
        for (int j = 0; j < 8; ++j) acc[i][j] = 0.f;

    for (int kc = 0; kc < 4; ++kc) {         // K chunks of 32
        __syncthreads();                     // previous chunk fully consumed
        {
            const float4* gs = (const float4*)(Ws + kc * 4096);
            const float4* gn = (const float4*)(Wn + kc * 4096);
            #pragma unroll
            for (int it = 0; it < 4; ++it) {
                int f4 = it * 256 + t;
                wsBuf[f4] = gs[f4];
                wnBuf[f4] = gn[f4];
            }
        }
        __syncthreads();
        #pragma unroll 2
        for (int kk8 = 0; kk8 < 4; ++kk8) {
            int sl = (lane & 48) | (kc * 4 + kk8);   // source lane for k in this 8-group
            #pragma unroll
            for (int u = 0; u < 8; ++u) {            // u literal -> static reg select
                int kl = kk8 * 8 + u;                // k within chunk
                float hb0 = __shfl(hreg[0][u], sl, 64);
                float hb1 = __shfl(hreg[1][u], sl, 64);
                float hb2 = __shfl(hreg[2][u], sl, 64);
                float hb3 = __shfl(hreg[3][u], sl, 64);
                float ab0 = __shfl(areg[0][u], sl, 64);
                float ab1 = __shfl(areg[1][u], sl, 64);
                float ab2 = __shfl(areg[2][u], sl, 64);
                float ab3 = __shfl(areg[3][u], sl, 64);
                float4 ws0 = wsBuf[kl * 32 + 2 * c], ws1 = wsBuf[kl * 32 + 2 * c + 1];
                float4 wn0 = wnBuf[kl * 32 + 2 * c], wn1 = wnBuf[kl * 32 + 2 * c + 1];
                float hv[4] = {hb0, hb1, hb2, hb3};
                float av[4] = {ab0, ab1, ab2, ab3};
                float wv[8] = {ws0.x, ws0.y, ws0.z, ws0.w, ws1.x, ws1.y, ws1.z, ws1.w};
                float uv[8] = {wn0.x, wn0.y, wn0.z, wn0.w, wn1.x, wn1.y, wn1.z, wn1.w};
                #pragma unroll
                for (int i = 0; i < 4; ++i)
                    #pragma unroll
                    for (int j = 0; j < 8; ++j)
                        acc[i][j] = fmaf(hv[i], wv[j], fmaf(av[i], uv[j], acc[i][j]));
            }
        }
    }
    float4 b0 = ((const float4*)bias)[2 * c], b1 = ((const float4*)bias)[2 * c + 1];
    float bv[8] = {b0.x, b0.y, b0.z, b0.w, b1.x, b1.y, b1.z, b1.w};
    #pragma unroll
    for (int i = 0; i < 4; ++i) {
        int row = row0 + 4 * g + i;
        if (row < NN) {
            float o[8];
            #pragma unroll
            for (int j = 0; j < 8; ++j) {
                float v = acc[i][j] + bv[j];
                if (RELU) v = fmaxf(v, 0.f);
                o[j] = v;
            }
            float4 s0 = {o[0], o[1], o[2], o[3]}, s1 = {o[4], o[5], o[6], o[7]};
            ((float4*)hout)[(size_t)row * 32 + 2 * c] = s0;
            ((float4*)hout)[(size_t)row * 32 + 2 * c + 1] = s1;
        }
    }
}

// ---------------- fused predictor: weights chunk-staged in LDS ----------------

__global__ __launch_bounds__(256) void k_pred(const float* __restrict__ h,
                                              const int* __restrict__ ps, const int* __restrict__ pd,
                                              const int* __restrict__ ns, const int* __restrict__ nd,
                                              const float* __restrict__ Wp1, const float* __restrict__ bp1,
                                              const float* __restrict__ Wp2, const float* __restrict__ bp2,
                                              const float* __restrict__ Wp3, const float* __restrict__ bp3,
                                              float* __restrict__ out) {
    __shared__ float4 wBuf[1024];            // 16 KB, reused by both GEMMs
    int t = threadIdx.x;
    int lane = t & 63;
    int g = t >> 4;
    int c = t & 15;
    int row0 = blockIdx.x * 64;
    float e[4][8];
    #pragma unroll
    for (int i = 0; i < 4; ++i) {
        int row = row0 + 4 * g + i;
        int s, d;
        if (row < NP) { s = ps[row]; d = pd[row]; }
        else          { s = ns[row - NP]; d = nd[row - NP]; }
        const float4* hs = (const float4*)(h + (size_t)s * DD);
        const float4* hd = (const float4*)(h + (size_t)d * DD);
        float4 a0 = hs[2 * c], a1 = hs[2 * c + 1];
        float4 b0 = hd[2 * c], b1 = hd[2 * c + 1];
        e[i][0] = a0.x * b0.x; e[i][1] = a0.y * b0.y; e[i][2] = a0.z * b0.z; e[i][3] = a0.w * b0.w;
        e[i][4] = a1.x * b1.x; e[i][5] = a1.y * b1.y; e[i][6] = a1.z * b1.z; e[i][7] = a1.w * b1.w;
    }
    float acc[4][8];
    #pragma unroll
    for (int i = 0; i < 4; ++i)
        #pragma unroll
        for (int j = 0; j < 8; ++j) acc[i][j] = 0.f;

    // GEMM1: acc = e @ Wp1
    for (int kc = 0; kc < 4; ++kc) {
        __syncthreads();
        {
            const float4* gw = (const float4*)(Wp1 + kc * 4096);
            #pragma unroll
            for (int it = 0; it < 4; ++it) wBuf[it * 256 + t] = gw[it * 256 + t];
        }
        __syncthreads();
        #pragma unroll 2
        for (int kk8 = 0; kk8 < 4; ++kk8) {
            int sl = (lane & 48) | (kc * 4 + kk8);
            #pragma unroll
            for (int u = 0; u < 8; ++u) {
                int kl = kk8 * 8 + u;
                float e0 = __shfl(e[0][u], sl, 64);
                float e1 = __shfl(e[1][u], sl, 64);
                float e2 = __shfl(e[2][u], sl, 64);
                float e3 = __shfl(e[3][u], sl, 64);
                float4 w0 = wBuf[kl * 32 + 2 * c], w1 = wBuf[kl * 32 + 2 * c + 1];
                float ev[4] = {e0, e1, e2, e3};
                float wv[8] = {w0.x, w0.y, w0.z, w0.w, w1.x, w1.y, w1.z, w1.w};
                #pragma unroll
                for (int i = 0; i < 4; ++i)
                    #pragma unroll
                    for (int j = 0; j < 8; ++j)
                        acc[i][j] = fmaf(ev[i], wv[j], acc[i][j]);
            }
        }
    }
    // z1 = relu(acc + bp1) -> reuse e; reset acc
    {
        float4 b0 = ((const float4*)bp1)[2 * c], b1 = ((const float4*)bp1)[2 * c + 1];
        float bv[8] = {b0.x, b0.y, b0.z, b0.w, b1.x, b1.y, b1.z, b1.w};
        #pragma unroll
        for (int i = 0; i < 4; ++i)
            #pragma unroll
            for (int j = 0; j < 8; ++j) {
                e[i][j] = fmaxf(acc[i][j] + bv[j], 0.f);
                acc[i][j] = 0.f;
            }
    }
    // GEMM2: acc = z1 @ Wp2
    for (int kc = 0; kc < 4; ++kc) {
        __syncthreads();
        {
            const float4* gw = (const float4*)(Wp2 + kc * 4096);
            #pragma unroll
            for (int it = 0; it < 4; ++it) wBuf[it * 256 + t] = gw[it * 256 + t];
        }
        __syncthreads();
        #pragma unroll 2
        for (int kk8 = 0; kk8 < 4; ++kk8) {
            int sl = (lane & 48) | (kc * 4 + kk8);
            #pragma unroll
            for (int u = 0; u < 8; ++u) {
                int kl = kk8 * 8 + u;
                float e0 = __shfl(e[0][u], sl, 64);
                float e1 = __shfl(e[1][u], sl, 64);
                float e2 = __shfl(e[2][u], sl, 64);
                float e3 = __shfl(e[3][u], sl, 64);
                float4 w0 = wBuf[kl * 32 + 2 * c], w1 = wBuf[kl * 32 + 2 * c + 1];
                float ev[4] = {e0, e1, e2, e3};
                float wv[8] = {w0.x, w0.y, w0.z, w0.w, w1.x, w1.y, w1.z, w1.w};
                #pragma unroll
                for (int i = 0; i < 4; ++i)
                    #pragma unroll
                    for (int j = 0; j < 8; ++j)
                        acc[i][j] = fmaf(ev[i], wv[j], acc[i][j]);
            }
        }
    }
    // z2 = relu(acc + bp2); dot with Wp3 cols 8c..8c+7; reduce over the 16 c-lanes
    float4 c0 = ((const float4*)bp2)[2 * c], c1 = ((const float4*)bp2)[2 * c + 1];
    float cv[8] = {c0.x, c0.y, c0.z, c0.w, c1.x, c1.y, c1.z, c1.w};
    float4 w30 = ((const float4*)Wp3)[2 * c], w31 = ((const float4*)Wp3)[2 * c + 1];
    float w3v[8] = {w30.x, w30.y, w30.z, w30.w, w31.x, w31.y, w31.z, w31.w};
    float p[4] = {0.f, 0.f, 0.f, 0.f};
    #pragma unroll
    for (int i = 0; i < 4; ++i)
        #pragma unroll
        for (int j = 0; j < 8; ++j)
            p[i] = fmaf(fmaxf(acc[i][j] + cv[j], 0.f), w3v[j], p[i]);
    #pragma unroll
    for (int off = 1; off < 16; off <<= 1) {
        #pragma unroll
        for (int i = 0; i < 4; ++i) p[i] += __shfl_xor(p[i], off, 64);
    }
    if (c == 0) {
        float bb = bp3[0];
        #pragma unroll
        for (int i = 0; i < 4; ++i) out[row0 + 4 * g + i] = p[i] + bb;
    }
}

// ---------------- launch ----------------

extern "C" void kernel_launch(void* const* d_in, const int* in_sizes, int n_in,
                              void* d_out, int out_size, void* d_ws, size_t ws_size,
                              hipStream_t stream) {
    const float* x      = (const float*)d_in[0];
    const float* W_self = (const float*)d_in[1];
    const float* W_neigh= (const float*)d_in[2];
    const float* b      = (const float*)d_in[3];
    const float* Wp1    = (const float*)d_in[4];
    const float* bp1    = (const float*)d_in[5];
    const float* Wp2    = (const float*)d_in[6];
    const float* bp2    = (const float*)d_in[7];
    const float* Wp3    = (const float*)d_in[8];
    const float* bp3    = (const float*)d_in[9];
    const int* edge_src = (const int*)d_in[10];
    const int* edge_dst = (const int*)d_in[11];
    const int* pos_src  = (const int*)d_in[12];
    const int* pos_dst  = (const int*)d_in[13];
    const int* neg_src  = (const int*)d_in[14];
    const int* neg_dst  = (const int*)d_in[15];
    float* out = (float*)d_out;

    size_t o = 0;
    char* base = (char*)d_ws;
    auto take = [&](size_t bytes) -> void* {
        void* r = base + o;
        o = (o + bytes + 255) & ~(size_t)255;
        return r;
    };
    int*   deg     = (int*)take(NN * 4);
    int*   cursor  = (int*)take(NN * 4);
    int*   row_ptr = (int*)take(50304 * 4);   // scan1 writes up to 50175; [NN]=50000 used
    int*   sums    = (int*)take(64 * 4);
    int*   csr     = (int*)take(NE * 4);
    float* inv_deg = (float*)take(NN * 4);
    float* aggm    = (float*)take((size_t)NN * DD * 4);
    float* hA      = (float*)take((size_t)NN * DD * 4);
    float* hB      = (float*)take((size_t)NN * DD * 4);
    (void)ws_size; (void)n_in; (void)in_sizes; (void)out_size;

    hipMemsetAsync(deg, 0, NN * 4, stream);
    hipMemsetAsync(cursor, 0, NN * 4, stream);

    k_count<<<(NE + 255) / 256, 256, 0, stream>>>(edge_dst, deg);
    k_scan1<<<49, 1024, 0, stream>>>(deg, row_ptr, sums);
    k_scan2<<<1, 64, 0, stream>>>(sums);
    k_scan3<<<(NN + 255) / 256, 256, 0, stream>>>(row_ptr, sums, deg, inv_deg);
    k_fill<<<(NE + 255) / 256, 256, 0, stream>>>(edge_src, edge_dst, row_ptr, cursor, csr);

    const int aggGrid = (NN + 3) / 4;          // 4 waves/block, wave per node
    const int layGrid = (NN + 63) / 64;        // 64 rows/block

    // layer 0: x -> hA
    k_agg<<<aggGrid, 256, 0, stream>>>(x, row_ptr, csr, inv_deg, aggm);
    k_layer<1><<<layGrid, 256, 0, stream>>>(x, aggm, W_self, W_neigh, b, hA);
    // layer 1: hA -> hB
    k_agg<<<aggGrid, 256, 0, stream>>>(hA, row_ptr, csr, inv_deg, aggm);
    k_layer<1><<<layGrid, 256, 0, stream>>>(hA, aggm, W_self + 16384, W_neigh + 16384, b + 128, hB);
    // layer 2 (no relu): hB -> hA
    k_agg<<<aggGrid, 256, 0, stream>>>(hB, row_ptr, csr, inv_deg, aggm);
    k_layer<0><<<layGrid, 256, 0, stream>>>(hB, aggm, W_self + 32768, W_neigh + 32768, b + 256, hA);

    k_pred<<<(2 * NP) / 64, 256, 0, stream>>>(hA, pos_src, pos_dst, neg_src, neg_dst,
                                              Wp1, bp1, Wp2, bp2, Wp3, bp3, out);
}

// Round 6
// 442.829 us; speedup vs baseline: 2.2585x; 1.7492x over previous
//
#include <hip/hip_runtime.h>

#define NN 50000
#define NE 600000
#define NP 100000
#define DD 128

typedef _Float16 f16;
typedef _Float16 f16x4 __attribute__((ext_vector_type(4)));
typedef _Float16 f16x8 __attribute__((ext_vector_type(8)));
typedef float f32x4v __attribute__((ext_vector_type(4)));

// ---------------- CSR build ----------------

__global__ __launch_bounds__(256) void k_count(const int* __restrict__ dst, int* __restrict__ deg) {
    int i = blockIdx.x * 256 + threadIdx.x;
    if (i < NE) atomicAdd(&deg[dst[i]], 1);
}

__global__ __launch_bounds__(1024) void k_scan1(const int* __restrict__ deg, int* __restrict__ excl,
                                                int* __restrict__ sums) {
    __shared__ int tmp[1024];
    int t = threadIdx.x;
    int gid = blockIdx.x * 1024 + t;
    int v = (gid < NN) ? deg[gid] : 0;
    tmp[t] = v;
    __syncthreads();
    #pragma unroll
    for (int off = 1; off < 1024; off <<= 1) {
        int u = (t >= off) ? tmp[t - off] : 0;
        __syncthreads();
        tmp[t] += u;
        __syncthreads();
    }
    excl[gid] = tmp[t] - v;
    if (t == 1023) sums[blockIdx.x] = tmp[t];
}

__global__ __launch_bounds__(64) void k_scan2(int* __restrict__ sums) {
    int t = threadIdx.x;
    int v = (t < 49) ? sums[t] : 0;
    int orig = v;
    #pragma unroll
    for (int off = 1; off < 64; off <<= 1) {
        int u = __shfl_up(v, off, 64);
        if (t >= off) v += u;
    }
    if (t < 64) sums[t] = v - orig;
}

__global__ __launch_bounds__(256) void k_scan3(int* __restrict__ row_ptr, const int* __restrict__ sums,
                                               const int* __restrict__ deg, float* __restrict__ inv_deg) {
    int i = blockIdx.x * 256 + threadIdx.x;
    if (i < NN) {
        row_ptr[i] += sums[i >> 10];
        int d = deg[i];
        inv_deg[i] = 1.0f / (float)(d > 1 ? d : 1);
        if (i == 0) row_ptr[NN] = NE;
    }
}

__global__ __launch_bounds__(256) void k_fill(const int* __restrict__ src, const int* __restrict__ dst,
                                              const int* __restrict__ row_ptr, int* __restrict__ cursor,
                                              int* __restrict__ csr) {
    int i = blockIdx.x * 256 + threadIdx.x;
    if (i < NE) {
        int d = dst[i];
        int p = row_ptr[d] + atomicAdd(&cursor[d], 1);
        csr[p] = src[i];
    }
}

// ---------------- mean aggregation: one wave per node ----------------

__global__ __launch_bounds__(256) void k_agg(const float* __restrict__ h, const int* __restrict__ row_ptr,
                                             const int* __restrict__ csr, const float* __restrict__ inv_deg,
                                             float* __restrict__ agg) {
    int wid = (int)((blockIdx.x * 256 + threadIdx.x) >> 6);
    int lane = threadIdx.x & 63;
    if (wid >= NN) return;
    int beg = row_ptr[wid], end = row_ptr[wid + 1];
    int half = lane >> 5, q = lane & 31;
    float4 s = {0.f, 0.f, 0.f, 0.f};
    int i = beg;
    for (; i + 4 <= end; i += 4) {
        int s0 = csr[i + half], s1 = csr[i + 2 + half];
        float4 v0 = ((const float4*)(h + (size_t)s0 * DD))[q];
        float4 v1 = ((const float4*)(h + (size_t)s1 * DD))[q];
        s.x += v0.x + v1.x; s.y += v0.y + v1.y; s.z += v0.z + v1.z; s.w += v0.w + v1.w;
    }
    for (; i + half < end; i += 2) {
        int s0 = csr[i + half];
        float4 v = ((const float4*)(h + (size_t)s0 * DD))[q];
        s.x += v.x; s.y += v.y; s.z += v.z; s.w += v.w;
    }
    s.x += __shfl_xor(s.x, 32, 64);
    s.y += __shfl_xor(s.y, 32, 64);
    s.z += __shfl_xor(s.z, 32, 64);
    s.w += __shfl_xor(s.w, 32, 64);
    if (half == 0) {
        float sc = inv_deg[wid];
        float4 o = {s.x * sc, s.y * sc, s.z * sc, s.w * sc};
        ((float4*)(agg + (size_t)wid * DD))[q] = o;
    }
}

// ---------------- weight prep: split fp32 -> f16 hi/lo, transposed [n][k] ----------------
// Layers: BT[l][n][k], k in 0..255 (k<128 -> W_self[l][k][n], else W_neigh[l][k-128][n]).
// Predictor: BT1/BT2 [n][k] of Wp1/Wp2.

__global__ __launch_bounds__(256) void k_prep(const float* __restrict__ Wsf, const float* __restrict__ Wng,
                                              const float* __restrict__ Wp1, const float* __restrict__ Wp2,
                                              f16* __restrict__ BTLh, f16* __restrict__ BTLl,
                                              f16* __restrict__ BT1h, f16* __restrict__ BT1l,
                                              f16* __restrict__ BT2h, f16* __restrict__ BT2l) {
    int idx = blockIdx.x * 256 + threadIdx.x;
    float wv;
    f16 *dh, *dl;
    int off;
    if (idx < 98304) {
        int l = idx >> 15;
        int rem = idx & 32767;
        int n = rem >> 8;
        int k = rem & 255;
        wv = (k < 128) ? Wsf[l * 16384 + k * 128 + n] : Wng[l * 16384 + (k - 128) * 128 + n];
        dh = BTLh; dl = BTLl; off = idx;
    } else if (idx < 114688) {
        int p = idx - 98304;
        int n = p >> 7, k = p & 127;
        wv = Wp1[k * 128 + n];
        dh = BT1h; dl = BT1l; off = p;
    } else {
        int p = idx - 114688;
        int n = p >> 7, k = p & 127;
        wv = Wp2[k * 128 + n];
        dh = BT2h; dl = BT2l; off = p;
    }
    f16 hi = (f16)wv;
    dh[off] = hi;
    dl[off] = (f16)(wv - (float)hi);
}

// ---------------- SAGE layer via MFMA: hout = relu?([hin|agg] @ [Ws;Wn] + b) ----------------
// Block 256 = 4 waves, M-tile 128 (32 rows/wave = 2 m-frags), N = 128 (8 n-frags), K = 256
// in chunks of 32. 3-term f16 split: Ah*Bh + Al*Bh + Ah*Bl. LDS rows padded to 40 f16
// (80 B stride -> 2-way bank aliasing max on ds_read_b128).

template <int RELU>
__global__ __launch_bounds__(256) void k_layer(const float* __restrict__ hin, const float* __restrict__ agg,
                                               const f16* __restrict__ BTh, const f16* __restrict__ BTl,
                                               const float* __restrict__ bias, float* __restrict__ hout) {
    __shared__ __align__(16) f16 Ah[128][40];
    __shared__ __align__(16) f16 Al[128][40];
    __shared__ __align__(16) f16 Bh[128][40];
    __shared__ __align__(16) f16 Bl[128][40];
    int t = threadIdx.x;
    int lane = t & 63;
    int w = t >> 6;
    int lo16 = lane & 15;
    int kg = lane >> 4;
    int row0 = blockIdx.x * 128;
    f32x4v acc[2][8];
    #pragma unroll
    for (int m = 0; m < 2; ++m)
        #pragma unroll
        for (int n = 0; n < 8; ++n) acc[m][n] = (f32x4v){0.f, 0.f, 0.f, 0.f};

    #pragma unroll 1
    for (int kc = 0; kc < 8; ++kc) {
        __syncthreads();
        {   // stage A chunk: 128 rows x 32 k fp32 -> hi/lo f16
            const float* src = (kc < 4) ? hin : agg;
            int kb = (kc & 3) * 8;               // float4 offset within row
            #pragma unroll
            for (int p = 0; p < 4; ++p) {
                int i = t + p * 256;
                int r = i >> 3, q = i & 7;
                float4 v = {0.f, 0.f, 0.f, 0.f};
                int gr = row0 + r;
                if (gr < NN) v = ((const float4*)src)[(size_t)gr * 32 + kb + q];
                f16x4 vh, vl;
                vh[0] = (f16)v.x; vl[0] = (f16)(v.x - (float)vh[0]);
                vh[1] = (f16)v.y; vl[1] = (f16)(v.y - (float)vh[1]);
                vh[2] = (f16)v.z; vl[2] = (f16)(v.z - (float)vh[2]);
                vh[3] = (f16)v.w; vl[3] = (f16)(v.w - (float)vh[3]);
                *(f16x4*)&Ah[r][4 * q] = vh;
                *(f16x4*)&Al[r][4 * q] = vl;
            }
        }
        {   // stage B chunk: pre-split BT[n][k] slices, straight copy
            #pragma unroll
            for (int p = 0; p < 2; ++p) {
                int i = t + p * 256;
                int n = i >> 2, j = i & 3;
                *(uint4*)&Bh[n][8 * j] = *(const uint4*)&BTh[n * 256 + kc * 32 + 8 * j];
                *(uint4*)&Bl[n][8 * j] = *(const uint4*)&BTl[n * 256 + kc * 32 + 8 * j];
            }
        }
        __syncthreads();
        f16x8 ah[2], al[2];
        #pragma unroll
        for (int m = 0; m < 2; ++m) {
            ah[m] = *(const f16x8*)&Ah[w * 32 + m * 16 + lo16][8 * kg];
            al[m] = *(const f16x8*)&Al[w * 32 + m * 16 + lo16][8 * kg];
        }
        #pragma unroll
        for (int n = 0; n < 8; ++n) {
            f16x8 bh = *(const f16x8*)&Bh[16 * n + lo16][8 * kg];
            f16x8 bl = *(const f16x8*)&Bl[16 * n + lo16][8 * kg];
            #pragma unroll
            for (int m = 0; m < 2; ++m) {
                acc[m][n] = __builtin_amdgcn_mfma_f32_16x16x32_f16(ah[m], bh, acc[m][n], 0, 0, 0);
                acc[m][n] = __builtin_amdgcn_mfma_f32_16x16x32_f16(al[m], bh, acc[m][n], 0, 0, 0);
                acc[m][n] = __builtin_amdgcn_mfma_f32_16x16x32_f16(ah[m], bl, acc[m][n], 0, 0, 0);
            }
        }
    }
    // epilogue: C frag (m,n): col = 16n + lo16, row = w*32 + m*16 + 4*kg + r
    #pragma unroll
    for (int m = 0; m < 2; ++m)
        #pragma unroll
        for (int r = 0; r < 4; ++r) {
            int row = row0 + w * 32 + m * 16 + kg * 4 + r;
            if (row < NN) {
                #pragma unroll
                for (int n = 0; n < 8; ++n) {
                    int col = 16 * n + lo16;
                    float v = acc[m][n][r] + bias[col];
                    if (RELU) v = fmaxf(v, 0.f);
                    hout[(size_t)row * 128 + col] = v;
                }
            }
        }
}

// ---------------- fused predictor via MFMA ----------------
// GEMM1: e = h[s]*h[d] gathered straight into A-frags (3-term); z1 = relu(+b1) kept
// f16 in LDS. GEMM2: 2-term (z1h * (Bh+Bl)). Epilogue: dot Wp3 + 16-lane reduce.

__global__ __launch_bounds__(256) void k_pred(const float* __restrict__ h,
                                              const int* __restrict__ ps, const int* __restrict__ pd,
                                              const int* __restrict__ ns, const int* __restrict__ nd,
                                              const f16* __restrict__ BT1h, const f16* __restrict__ BT1l,
                                              const f16* __restrict__ BT2h, const f16* __restrict__ BT2l,
                                              const float* __restrict__ bp1, const float* __restrict__ bp2,
                                              const float* __restrict__ Wp3, const float* __restrict__ bp3,
                                              float* __restrict__ out) {
    __shared__ __align__(16) f16 Z[128][136];
    __shared__ __align__(16) f16 Bh[128][40];
    __shared__ __align__(16) f16 Bl[128][40];
    int t = threadIdx.x;
    int lane = t & 63;
    int w = t >> 6;
    int lo16 = lane & 15;
    int kg = lane >> 4;
    int row0 = blockIdx.x * 128;
    int sIdx[2], dIdx[2];
    #pragma unroll
    for (int m = 0; m < 2; ++m) {
        int row = row0 + w * 32 + m * 16 + lo16;
        int s = 0, d = 0;
        if (row < NP)           { s = ps[row];      d = pd[row]; }
        else if (row < 2 * NP)  { s = ns[row - NP]; d = nd[row - NP]; }
        sIdx[m] = s; dIdx[m] = d;
    }
    f32x4v acc[2][8];
    #pragma unroll
    for (int m = 0; m < 2; ++m)
        #pragma unroll
        for (int n = 0; n < 8; ++n) acc[m][n] = (f32x4v){0.f, 0.f, 0.f, 0.f};

    // ---- GEMM1: acc = e @ Wp1 (3-term) ----
    #pragma unroll 1
    for (int kc = 0; kc < 4; ++kc) {
        __syncthreads();
        #pragma unroll
        for (int p = 0; p < 2; ++p) {
            int i = t + p * 256;
            int n = i >> 2, j = i & 3;
            *(uint4*)&Bh[n][8 * j] = *(const uint4*)&BT1h[n * 128 + kc * 32 + 8 * j];
            *(uint4*)&Bl[n][8 * j] = *(const uint4*)&BT1l[n * 128 + kc * 32 + 8 * j];
        }
        __syncthreads();
        f16x8 eh[2], el[2];
        #pragma unroll
        for (int m = 0; m < 2; ++m) {
            const float4* hs = (const float4*)(h + (size_t)sIdx[m] * 128);
            const float4* hd = (const float4*)(h + (size_t)dIdx[m] * 128);
            int q0 = kc * 8 + kg * 2;
            float4 a0 = hs[q0], a1 = hs[q0 + 1];
            float4 b0 = hd[q0], b1 = hd[q0 + 1];
            float e[8] = {a0.x * b0.x, a0.y * b0.y, a0.z * b0.z, a0.w * b0.w,
                          a1.x * b1.x, a1.y * b1.y, a1.z * b1.z, a1.w * b1.w};
            #pragma unroll
            for (int q = 0; q < 8; ++q) {
                f16 hi = (f16)e[q];
                eh[m][q] = hi;
                el[m][q] = (f16)(e[q] - (float)hi);
            }
        }
        #pragma unroll
        for (int n = 0; n < 8; ++n) {
            f16x8 bh = *(const f16x8*)&Bh[16 * n + lo16][8 * kg];
            f16x8 bl = *(const f16x8*)&Bl[16 * n + lo16][8 * kg];
            #pragma unroll
            for (int m = 0; m < 2; ++m) {
                acc[m][n] = __builtin_amdgcn_mfma_f32_16x16x32_f16(eh[m], bh, acc[m][n], 0, 0, 0);
                acc[m][n] = __builtin_amdgcn_mfma_f32_16x16x32_f16(el[m], bh, acc[m][n], 0, 0, 0);
                acc[m][n] = __builtin_amdgcn_mfma_f32_16x16x32_f16(eh[m], bl, acc[m][n], 0, 0, 0);
            }
        }
    }
    // z1 = relu(acc + bp1) -> LDS (f16 hi only; error ~2^-11 rel, within budget)
    #pragma unroll
    for (int m = 0; m < 2; ++m)
        #pragma unroll
        for (int n = 0; n < 8; ++n) {
            int col = 16 * n + lo16;
            float bv = bp1[col];
            #pragma unroll
            for (int r = 0; r < 4; ++r) {
                float z = fmaxf(acc[m][n][r] + bv, 0.f);
                Z[w * 32 + m * 16 + kg * 4 + r][col] = (f16)z;
            }
        }

    // ---- GEMM2: acc2 = z1 @ Wp2 (2-term) ----
    f32x4v acc2[2][8];
    #pragma unroll
    for (int m = 0; m < 2; ++m)
        #pragma unroll
        for (int n = 0; n < 8; ++n) acc2[m][n] = (f32x4v){0.f, 0.f, 0.f, 0.f};
    #pragma unroll 1
    for (int kc = 0; kc < 4; ++kc) {
        __syncthreads();   // protects Z writes (first iter) and prior B reads
        #pragma unroll
        for (int p = 0; p < 2; ++p) {
            int i = t + p * 256;
            int n = i >> 2, j = i & 3;
            *(uint4*)&Bh[n][8 * j] = *(const uint4*)&BT2h[n * 128 + kc * 32 + 8 * j];
            *(uint4*)&Bl[n][8 * j] = *(const uint4*)&BT2l[n * 128 + kc * 32 + 8 * j];
        }
        __syncthreads();
        f16x8 zf[2];
        #pragma unroll
        for (int m = 0; m < 2; ++m)
            zf[m] = *(const f16x8*)&Z[w * 32 + m * 16 + lo16][kc * 32 + 8 * kg];
        #pragma unroll
        for (int n = 0; n < 8; ++n) {
            f16x8 bh = *(const f16x8*)&Bh[16 * n + lo16][8 * kg];
            f16x8 bl = *(const f16x8*)&Bl[16 * n + lo16][8 * kg];
            #pragma unroll
            for (int m = 0; m < 2; ++m) {
                acc2[m][n] = __builtin_amdgcn_mfma_f32_16x16x32_f16(zf[m], bh, acc2[m][n], 0, 0, 0);
                acc2[m][n] = __builtin_amdgcn_mfma_f32_16x16x32_f16(zf[m], bl, acc2[m][n], 0, 0, 0);
            }
        }
    }
    // epilogue: p = sum_col relu(acc2 + bp2) * Wp3, reduce over the 16 col-lanes
    float p[2][4] = {{0.f, 0.f, 0.f, 0.f}, {0.f, 0.f, 0.f, 0.f}};
    #pragma unroll
    for (int m = 0; m < 2; ++m)
        #pragma unroll
        for (int n = 0; n < 8; ++n) {
            int col = 16 * n + lo16;
            float bv = bp2[col], w3 = Wp3[col];
            #pragma unroll
            for (int r = 0; r < 4; ++r)
                p[m][r] = fmaf(fmaxf(acc2[m][n][r] + bv, 0.f), w3, p[m][r]);
        }
    #pragma unroll
    for (int off = 1; off < 16; off <<= 1) {
        #pragma unroll
        for (int m = 0; m < 2; ++m)
            #pragma unroll
            for (int r = 0; r < 4; ++r)
                p[m][r] += __shfl_xor(p[m][r], off, 64);
    }
    if (lo16 == 0) {
        float bb = bp3[0];
        #pragma unroll
        for (int m = 0; m < 2; ++m)
            #pragma unroll
            for (int r = 0; r < 4; ++r) {
                int row = row0 + w * 32 + m * 16 + kg * 4 + r;
                if (row < 2 * NP) out[row] = p[m][r] + bb;
            }
    }
}

// ---------------- launch ----------------

extern "C" void kernel_launch(void* const* d_in, const int* in_sizes, int n_in,
                              void* d_out, int out_size, void* d_ws, size_t ws_size,
                              hipStream_t stream) {
    const float* x      = (const float*)d_in[0];
    const float* W_self = (const float*)d_in[1];
    const float* W_neigh= (const float*)d_in[2];
    const float* b      = (const float*)d_in[3];
    const float* Wp1    = (const float*)d_in[4];
    const float* bp1    = (const float*)d_in[5];
    const float* Wp2    = (const float*)d_in[6];
    const float* bp2    = (const float*)d_in[7];
    const float* Wp3    = (const float*)d_in[8];
    const float* bp3    = (const float*)d_in[9];
    const int* edge_src = (const int*)d_in[10];
    const int* edge_dst = (const int*)d_in[11];
    const int* pos_src  = (const int*)d_in[12];
    const int* pos_dst  = (const int*)d_in[13];
    const int* neg_src  = (const int*)d_in[14];
    const int* neg_dst  = (const int*)d_in[15];
    float* out = (float*)d_out;

    size_t o = 0;
    char* base = (char*)d_ws;
    auto take = [&](size_t bytes) -> void* {
        void* r = base + o;
        o = (o + bytes + 255) & ~(size_t)255;
        return r;
    };
    int*   deg     = (int*)take(NN * 4);
    int*   cursor  = (int*)take(NN * 4);
    int*   row_ptr = (int*)take(50304 * 4);
    int*   sums    = (int*)take(64 * 4);
    int*   csr     = (int*)take(NE * 4);
    float* inv_deg = (float*)take(NN * 4);
    float* aggm    = (float*)take((size_t)NN * DD * 4);
    float* hA      = (float*)take((size_t)NN * DD * 4);
    float* hB      = (float*)take((size_t)NN * DD * 4);
    f16*   BTLh    = (f16*)take(98304 * 2);
    f16*   BTLl    = (f16*)take(98304 * 2);
    f16*   BT1h    = (f16*)take(16384 * 2);
    f16*   BT1l    = (f16*)take(16384 * 2);
    f16*   BT2h    = (f16*)take(16384 * 2);
    f16*   BT2l    = (f16*)take(16384 * 2);
    (void)ws_size; (void)n_in; (void)in_sizes; (void)out_size;

    hipMemsetAsync(deg, 0, NN * 4, stream);
    hipMemsetAsync(cursor, 0, NN * 4, stream);

    k_prep<<<512, 256, 0, stream>>>(W_self, W_neigh, Wp1, Wp2, BTLh, BTLl, BT1h, BT1l, BT2h, BT2l);

    k_count<<<(NE + 255) / 256, 256, 0, stream>>>(edge_dst, deg);
    k_scan1<<<49, 1024, 0, stream>>>(deg, row_ptr, sums);
    k_scan2<<<1, 64, 0, stream>>>(sums);
    k_scan3<<<(NN + 255) / 256, 256, 0, stream>>>(row_ptr, sums, deg, inv_deg);
    k_fill<<<(NE + 255) / 256, 256, 0, stream>>>(edge_src, edge_dst, row_ptr, cursor, csr);

    const int aggGrid = (NN + 3) / 4;
    const int layGrid = (NN + 127) / 128;

    // layer 0: x -> hA
    k_agg<<<aggGrid, 256, 0, stream>>>(x, row_ptr, csr, inv_deg, aggm);
    k_layer<1><<<layGrid, 256, 0, stream>>>(x, aggm, BTLh, BTLl, b, hA);
    // layer 1: hA -> hB
    k_agg<<<aggGrid, 256, 0, stream>>>(hA, row_ptr, csr, inv_deg, aggm);
    k_layer<1><<<layGrid, 256, 0, stream>>>(hA, aggm, BTLh + 32768, BTLl + 32768, b + 128, hB);
    // layer 2 (no relu): hB -> hA
    k_agg<<<aggGrid, 256, 0, stream>>>(hB, row_ptr, csr, inv_deg, aggm);
    k_layer<0><<<layGrid, 256, 0, stream>>>(hB, aggm, BTLh + 65536, BTLl + 65536, b + 256, hA);

    k_pred<<<(2 * NP + 127) / 128, 256, 0, stream>>>(hA, pos_src, pos_dst, neg_src, neg_dst,
                                                     BT1h, BT1l, BT2h, BT2l,
                                                     bp1, bp2, Wp3, bp3, out);
}

// Round 9
// 403.964 us; speedup vs baseline: 2.4758x; 1.0962x over previous
//
#include <hip/hip_runtime.h>

#define NN 50000
#define NE 600000
#define NP 100000
#define DD 128

typedef _Float16 f16;
typedef _Float16 f16x4 __attribute__((ext_vector_type(4)));
typedef _Float16 f16x8 __attribute__((ext_vector_type(8)));
typedef float f32x4v __attribute__((ext_vector_type(4)));

// ---------------- CSR build ----------------

__global__ __launch_bounds__(256) void k_count(const int* __restrict__ dst, int* __restrict__ deg) {
    int i = blockIdx.x * 256 + threadIdx.x;
    if (i < NE) atomicAdd(&deg[dst[i]], 1);
}

__global__ __launch_bounds__(1024) void k_scan1(const int* __restrict__ deg, int* __restrict__ excl,
                                                int* __restrict__ sums) {
    __shared__ int tmp[1024];
    int t = threadIdx.x;
    int gid = blockIdx.x * 1024 + t;
    int v = (gid < NN) ? deg[gid] : 0;
    tmp[t] = v;
    __syncthreads();
    #pragma unroll
    for (int off = 1; off < 1024; off <<= 1) {
        int u = (t >= off) ? tmp[t - off] : 0;
        __syncthreads();
        tmp[t] += u;
        __syncthreads();
    }
    excl[gid] = tmp[t] - v;
    if (t == 1023) sums[blockIdx.x] = tmp[t];
}

__global__ __launch_bounds__(64) void k_scan2(int* __restrict__ sums) {
    int t = threadIdx.x;
    int v = (t < 49) ? sums[t] : 0;
    int orig = v;
    #pragma unroll
    for (int off = 1; off < 64; off <<= 1) {
        int u = __shfl_up(v, off, 64);
        if (t >= off) v += u;
    }
    if (t < 64) sums[t] = v - orig;
}

__global__ __launch_bounds__(256) void k_scan3(int* __restrict__ row_ptr, const int* __restrict__ sums,
                                               const int* __restrict__ deg, float* __restrict__ inv_deg) {
    int i = blockIdx.x * 256 + threadIdx.x;
    if (i < NN) {
        row_ptr[i] += sums[i >> 10];
        int d = deg[i];
        inv_deg[i] = 1.0f / (float)(d > 1 ? d : 1);
        if (i == 0) row_ptr[NN] = NE;
    }
}

__global__ __launch_bounds__(256) void k_fill(const int* __restrict__ src, const int* __restrict__ dst,
                                              const int* __restrict__ row_ptr, int* __restrict__ cursor,
                                              int* __restrict__ csr) {
    int i = blockIdx.x * 256 + threadIdx.x;
    if (i < NE) {
        int d = dst[i];
        int p = row_ptr[d] + atomicAdd(&cursor[d], 1);
        csr[p] = src[i];
    }
}

// ---------------- cast x -> f16 shadow ----------------

__global__ __launch_bounds__(256) void k_cast(const float* __restrict__ x, f16* __restrict__ x16) {
    int i = blockIdx.x * 256 + threadIdx.x;      // one float4 per thread; grid covers NN*DD/4
    float4 v = ((const float4*)x)[i];
    f16x4 o;
    o[0] = (f16)v.x; o[1] = (f16)v.y; o[2] = (f16)v.z; o[3] = (f16)v.w;
    *(f16x4*)(x16 + 4 * (size_t)i) = o;
}

// ---------------- mean aggregation from f16 rows: one wave per node ----------------
// lane = 16*grp + sl: grp in 0..3 picks neighbor slot, sl picks 16B (8 f16) of row.
// 4 rows in flight per load-step, fp32 accumulate, cross-group shfl reduce.

__global__ __launch_bounds__(256) void k_agg16(const f16* __restrict__ h16, const int* __restrict__ row_ptr,
                                               const int* __restrict__ csr, const float* __restrict__ inv_deg,
                                               float* __restrict__ agg) {
    int wid = (int)((blockIdx.x * 256 + threadIdx.x) >> 6);
    int lane = threadIdx.x & 63;
    if (wid >= NN) return;
    int beg = row_ptr[wid], end = row_ptr[wid + 1];
    int grp = lane >> 4, sl = lane & 15;
    float acc[8] = {0.f, 0.f, 0.f, 0.f, 0.f, 0.f, 0.f, 0.f};
    int i = beg;
    for (; i + 8 <= end; i += 8) {               // 2 independent row loads in flight
        int s0 = csr[i + grp], s1 = csr[i + 4 + grp];
        f16x8 v0 = *(const f16x8*)(h16 + (size_t)s0 * DD + 8 * sl);
        f16x8 v1 = *(const f16x8*)(h16 + (size_t)s1 * DD + 8 * sl);
        #pragma unroll
        for (int q = 0; q < 8; ++q) acc[q] += (float)v0[q] + (float)v1[q];
    }
    for (; i + grp < end; i += 4) {
        int s0 = csr[i + grp];
        f16x8 v = *(const f16x8*)(h16 + (size_t)s0 * DD + 8 * sl);
        #pragma unroll
        for (int q = 0; q < 8; ++q) acc[q] += (float)v[q];
    }
    #pragma unroll
    for (int q = 0; q < 8; ++q) {
        acc[q] += __shfl_xor(acc[q], 16, 64);
        acc[q] += __shfl_xor(acc[q], 32, 64);
    }
    if (grp == 0) {
        float sc = inv_deg[wid];
        float4 o0 = {acc[0] * sc, acc[1] * sc, acc[2] * sc, acc[3] * sc};
        float4 o1 = {acc[4] * sc, acc[5] * sc, acc[6] * sc, acc[7] * sc};
        float4* dst = (float4*)(agg + (size_t)wid * DD + 8 * sl);
        dst[0] = o0; dst[1] = o1;
    }
}

// ---------------- weight prep: split fp32 -> f16 hi/lo, transposed [n][k] ----------------

__global__ __launch_bounds__(256) void k_prep(const float* __restrict__ Wsf, const float* __restrict__ Wng,
                                              const float* __restrict__ Wp1, const float* __restrict__ Wp2,
                                              f16* __restrict__ BTLh, f16* __restrict__ BTLl,
                                              f16* __restrict__ BT1h, f16* __restrict__ BT1l,
                                              f16* __restrict__ BT2h, f16* __restrict__ BT2l) {
    int idx = blockIdx.x * 256 + threadIdx.x;
    float wv;
    f16 *dh, *dl;
    int off;
    if (idx < 98304) {
        int l = idx >> 15;
        int rem = idx & 32767;
        int n = rem >> 8;
        int k = rem & 255;
        wv = (k < 128) ? Wsf[l * 16384 + k * 128 + n] : Wng[l * 16384 + (k - 128) * 128 + n];
        dh = BTLh; dl = BTLl; off = idx;
    } else if (idx < 114688) {
        int p = idx - 98304;
        int n = p >> 7, k = p & 127;
        wv = Wp1[k * 128 + n];
        dh = BT1h; dl = BT1l; off = p;
    } else {
        int p = idx - 114688;
        int n = p >> 7, k = p & 127;
        wv = Wp2[k * 128 + n];
        dh = BT2h; dl = BT2l; off = p;
    }
    f16 hi = (f16)wv;
    dh[off] = hi;
    dl[off] = (f16)(wv - (float)hi);
}

// ---------------- SAGE layer via MFMA ----------------
// Block 256 = 4 waves, M-tile 128, N = 128, K = 256 in chunks of 32.
// 3-term f16 split. Optionally dual-writes f16 shadow for the next k_agg16.

template <int RELU, int W16>
__global__ __launch_bounds__(256) void k_layer(const float* __restrict__ hin, const float* __restrict__ agg,
                                               const f16* __restrict__ BTh, const f16* __restrict__ BTl,
                                               const float* __restrict__ bias, float* __restrict__ hout,
                                               f16* __restrict__ hout16) {
    __shared__ __align__(16) f16 Ah[128][40];
    __shared__ __align__(16) f16 Al[128][40];
    __shared__ __align__(16) f16 Bh[128][40];
    __shared__ __align__(16) f16 Bl[128][40];
    int t = threadIdx.x;
    int lane = t & 63;
    int w = t >> 6;
    int lo16 = lane & 15;
    int kg = lane >> 4;
    int row0 = blockIdx.x * 128;
    f32x4v acc[2][8];
    #pragma unroll
    for (int m = 0; m < 2; ++m)
        #pragma unroll
        for (int n = 0; n < 8; ++n) acc[m][n] = (f32x4v){0.f, 0.f, 0.f, 0.f};

    #pragma unroll 1
    for (int kc = 0; kc < 8; ++kc) {
        __syncthreads();
        {   // stage A chunk: 128 rows x 32 k fp32 -> hi/lo f16
            const float* src = (kc < 4) ? hin : agg;
            int kb = (kc & 3) * 8;
            #pragma unroll
            for (int p = 0; p < 4; ++p) {
                int i = t + p * 256;
                int r = i >> 3, q = i & 7;
                float4 v = {0.f, 0.f, 0.f, 0.f};
                int gr = row0 + r;
                if (gr < NN) v = ((const float4*)src)[(size_t)gr * 32 + kb + q];
                f16x4 vh, vl;
                vh[0] = (f16)v.x; vl[0] = (f16)(v.x - (float)vh[0]);
                vh[1] = (f16)v.y; vl[1] = (f16)(v.y - (float)vh[1]);
                vh[2] = (f16)v.z; vl[2] = (f16)(v.z - (float)vh[2]);
                vh[3] = (f16)v.w; vl[3] = (f16)(v.w - (float)vh[3]);
                *(f16x4*)&Ah[r][4 * q] = vh;
                *(f16x4*)&Al[r][4 * q] = vl;
            }
        }
        {   // stage B chunk: pre-split BT[n][k] slices
            #pragma unroll
            for (int p = 0; p < 2; ++p) {
                int i = t + p * 256;
                int n = i >> 2, j = i & 3;
                *(uint4*)&Bh[n][8 * j] = *(const uint4*)&BTh[n * 256 + kc * 32 + 8 * j];
                *(uint4*)&Bl[n][8 * j] = *(const uint4*)&BTl[n * 256 + kc * 32 + 8 * j];
            }
        }
        __syncthreads();
        f16x8 ah[2], al[2];
        #pragma unroll
        for (int m = 0; m < 2; ++m) {
            ah[m] = *(const f16x8*)&Ah[w * 32 + m * 16 + lo16][8 * kg];
            al[m] = *(const f16x8*)&Al[w * 32 + m * 16 + lo16][8 * kg];
        }
        #pragma unroll
        for (int n = 0; n < 8; ++n) {
            f16x8 bh = *(const f16x8*)&Bh[16 * n + lo16][8 * kg];
            f16x8 bl = *(const f16x8*)&Bl[16 * n + lo16][8 * kg];
            #pragma unroll
            for (int m = 0; m < 2; ++m) {
                acc[m][n] = __builtin_amdgcn_mfma_f32_16x16x32_f16(ah[m], bh, acc[m][n], 0, 0, 0);
                acc[m][n] = __builtin_amdgcn_mfma_f32_16x16x32_f16(al[m], bh, acc[m][n], 0, 0, 0);
                acc[m][n] = __builtin_amdgcn_mfma_f32_16x16x32_f16(ah[m], bl, acc[m][n], 0, 0, 0);
            }
        }
    }
    // epilogue: C frag (m,n): col = 16n + lo16, row = w*32 + m*16 + 4*kg + r
    #pragma unroll
    for (int m = 0; m < 2; ++m)
        #pragma unroll
        for (int r = 0; r < 4; ++r) {
            int row = row0 + w * 32 + m * 16 + kg * 4 + r;
            if (row < NN) {
                #pragma unroll
                for (int n = 0; n < 8; ++n) {
                    int col = 16 * n + lo16;
                    float v = acc[m][n][r] + bias[col];
                    if (RELU) v = fmaxf(v, 0.f);
                    hout[(size_t)row * 128 + col] = v;
                    if (W16) hout16[(size_t)row * 128 + col] = (f16)v;
                }
            }
        }
}

// ---------------- fused predictor via MFMA (Z split in halves for LDS) ----------------

__global__ __launch_bounds__(256) void k_pred(const float* __restrict__ h,
                                              const int* __restrict__ ps, const int* __restrict__ pd,
                                              const int* __restrict__ ns, const int* __restrict__ nd,
                                              const f16* __restrict__ BT1h, const f16* __restrict__ BT1l,
                                              const f16* __restrict__ BT2h, const f16* __restrict__ BT2l,
                                              const float* __restrict__ bp1, const float* __restrict__ bp2,
                                              const float* __restrict__ Wp3, const float* __restrict__ bp3,
                                              float* __restrict__ out) {
    __shared__ __align__(16) f16 Z2[128][72];    // half of z1 (64 cols + pad)
    __shared__ __align__(16) f16 Bh[128][40];
    __shared__ __align__(16) f16 Bl[128][40];
    int t = threadIdx.x;
    int lane = t & 63;
    int w = t >> 6;
    int lo16 = lane & 15;
    int kg = lane >> 4;
    int row0 = blockIdx.x * 128;
    int sIdx[2], dIdx[2];
    #pragma unroll
    for (int m = 0; m < 2; ++m) {
        int row = row0 + w * 32 + m * 16 + lo16;
        int s = 0, d = 0;
        if (row < NP)           { s = ps[row];      d = pd[row]; }
        else if (row < 2 * NP)  { s = ns[row - NP]; d = nd[row - NP]; }
        sIdx[m] = s; dIdx[m] = d;
    }
    f32x4v acc[2][8];
    #pragma unroll
    for (int m = 0; m < 2; ++m)
        #pragma unroll
        for (int n = 0; n < 8; ++n) acc[m][n] = (f32x4v){0.f, 0.f, 0.f, 0.f};

    // ---- GEMM1: acc = e @ Wp1 (3-term) ----
    #pragma unroll 1
    for (int kc = 0; kc < 4; ++kc) {
        __syncthreads();
        #pragma unroll
        for (int p = 0; p < 2; ++p) {
            int i = t + p * 256;
            int n = i >> 2, j = i & 3;
            *(uint4*)&Bh[n][8 * j] = *(const uint4*)&BT1h[n * 128 + kc * 32 + 8 * j];
            *(uint4*)&Bl[n][8 * j] = *(const uint4*)&BT1l[n * 128 + kc * 32 + 8 * j];
        }
        __syncthreads();
        f16x8 eh[2], el[2];
        #pragma unroll
        for (int m = 0; m < 2; ++m) {
            const float4* hs = (const float4*)(h + (size_t)sIdx[m] * 128);
            const float4* hd = (const float4*)(h + (size_t)dIdx[m] * 128);
            int q0 = kc * 8 + kg * 2;
            float4 a0 = hs[q0], a1 = hs[q0 + 1];
            float4 b0 = hd[q0], b1 = hd[q0 + 1];
            float e[8] = {a0.x * b0.x, a0.y * b0.y, a0.z * b0.z, a0.w * b0.w,
                          a1.x * b1.x, a1.y * b1.y, a1.z * b1.z, a1.w * b1.w};
            #pragma unroll
            for (int q = 0; q < 8; ++q) {
                f16 hi = (f16)e[q];
                eh[m][q] = hi;
                el[m][q] = (f16)(e[q] - (float)hi);
            }
        }
        #pragma unroll
        for (int n = 0; n < 8; ++n) {
            f16x8 bh = *(const f16x8*)&Bh[16 * n + lo16][8 * kg];
            f16x8 bl = *(const f16x8*)&Bl[16 * n + lo16][8 * kg];
            #pragma unroll
            for (int m = 0; m < 2; ++m) {
                acc[m][n] = __builtin_amdgcn_mfma_f32_16x16x32_f16(eh[m], bh, acc[m][n], 0, 0, 0);
                acc[m][n] = __builtin_amdgcn_mfma_f32_16x16x32_f16(el[m], bh, acc[m][n], 0, 0, 0);
                acc[m][n] = __builtin_amdgcn_mfma_f32_16x16x32_f16(eh[m], bl, acc[m][n], 0, 0, 0);
            }
        }
    }
    // z1 half B (cols 64..127) parked in registers as f16
    f16x4 zb[2][4];
    #pragma unroll
    for (int m = 0; m < 2; ++m)
        #pragma unroll
        for (int n = 0; n < 4; ++n) {
            float bv = bp1[16 * (n + 4) + lo16];
            #pragma unroll
            for (int r = 0; r < 4; ++r)
                zb[m][n][r] = (f16)fmaxf(acc[m][n + 4][r] + bv, 0.f);
        }

    // ---- GEMM2: acc2 = z1 @ Wp2 (2-term), Z2 holds 64 cols at a time ----
    f32x4v acc2[2][8];
    #pragma unroll
    for (int m = 0; m < 2; ++m)
        #pragma unroll
        for (int n = 0; n < 8; ++n) acc2[m][n] = (f32x4v){0.f, 0.f, 0.f, 0.f};
    #pragma unroll 1
    for (int kc = 0; kc < 4; ++kc) {
        __syncthreads();                         // prior B reads / prior Z2 reads done
        if (kc == 0) {                           // write half A (cols 0..63) = relu(acc n 0..3 + b)
            #pragma unroll
            for (int m = 0; m < 2; ++m)
                #pragma unroll
                for (int n = 0; n < 4; ++n) {
                    int col = 16 * n + lo16;
                    float bv = bp1[col];
                    #pragma unroll
                    for (int r = 0; r < 4; ++r)
                        Z2[w * 32 + m * 16 + kg * 4 + r][col] = (f16)fmaxf(acc[m][n][r] + bv, 0.f);
                }
        }
        if (kc == 2) {                           // overwrite with half B from registers
            #pragma unroll
            for (int m = 0; m < 2; ++m)
                #pragma unroll
                for (int n = 0; n < 4; ++n)
                    #pragma unroll
                    for (int r = 0; r < 4; ++r)
                        Z2[w * 32 + m * 16 + kg * 4 + r][16 * n + lo16] = zb[m][n][r];
        }
        #pragma unroll
        for (int p = 0; p < 2; ++p) {
            int i = t + p * 256;
            int n = i >> 2, j = i & 3;
            *(uint4*)&Bh[n][8 * j] = *(const uint4*)&BT2h[n * 128 + kc * 32 + 8 * j];
            *(uint4*)&Bl[n][8 * j] = *(const uint4*)&BT2l[n * 128 + kc * 32 + 8 * j];
        }
        __syncthreads();
        f16x8 zf[2];
        #pragma unroll
        for (int m = 0; m < 2; ++m)
            zf[m] = *(const f16x8*)&Z2[w * 32 + m * 16 + lo16][(kc & 1) * 32 + 8 * kg];
        #pragma unroll
        for (int n = 0; n < 8; ++n) {
            f16x8 bh = *(const f16x8*)&Bh[16 * n + lo16][8 * kg];
            f16x8 bl = *(const f16x8*)&Bl[16 * n + lo16][8 * kg];
            #pragma unroll
            for (int m = 0; m < 2; ++m) {
                acc2[m][n] = __builtin_amdgcn_mfma_f32_16x16x32_f16(zf[m], bh, acc2[m][n], 0, 0, 0);
                acc2[m][n] = __builtin_amdgcn_mfma_f32_16x16x32_f16(zf[m], bl, acc2[m][n], 0, 0, 0);
            }
        }
    }
    // epilogue: p = sum_col relu(acc2 + bp2) * Wp3, reduce over the 16 col-lanes
    float p[2][4] = {{0.f, 0.f, 0.f, 0.f}, {0.f, 0.f, 0.f, 0.f}};
    #pragma unroll
    for (int m = 0; m < 2; ++m)
        #pragma unroll
        for (int n = 0; n < 8; ++n) {
            int col = 16 * n + lo16;
            float bv = bp2[col], w3 = Wp3[col];
            #pragma unroll
            for (int r = 0; r < 4; ++r)
                p[m][r] = fmaf(fmaxf(acc2[m][n][r] + bv, 0.f), w3, p[m][r]);
        }
    #pragma unroll
    for (int off = 1; off < 16; off <<= 1) {
        #pragma unroll
        for (int m = 0; m < 2; ++m)
            #pragma unroll
            for (int r = 0; r < 4; ++r)
                p[m][r] += __shfl_xor(p[m][r], off, 64);
    }
    if (lo16 == 0) {
        float bb = bp3[0];
        #pragma unroll
        for (int m = 0; m < 2; ++m)
            #pragma unroll
            for (int r = 0; r < 4; ++r) {
                int row = row0 + w * 32 + m * 16 + kg * 4 + r;
                if (row < 2 * NP) out[row] = p[m][r] + bb;
            }
    }
}

// ---------------- launch ----------------

extern "C" void kernel_launch(void* const* d_in, const int* in_sizes, int n_in,
                              void* d_out, int out_size, void* d_ws, size_t ws_size,
                              hipStream_t stream) {
    const float* x      = (const float*)d_in[0];
    const float* W_self = (const float*)d_in[1];
    const float* W_neigh= (const float*)d_in[2];
    const float* b      = (const float*)d_in[3];
    const float* Wp1    = (const float*)d_in[4];
    const float* bp1    = (const float*)d_in[5];
    const float* Wp2    = (const float*)d_in[6];
    const float* bp2    = (const float*)d_in[7];
    const float* Wp3    = (const float*)d_in[8];
    const float* bp3    = (const float*)d_in[9];
    const int* edge_src = (const int*)d_in[10];
    const int* edge_dst = (const int*)d_in[11];
    const int* pos_src  = (const int*)d_in[12];
    const int* pos_dst  = (const int*)d_in[13];
    const int* neg_src  = (const int*)d_in[14];
    const int* neg_dst  = (const int*)d_in[15];
    float* out = (float*)d_out;

    size_t o = 0;
    char* base = (char*)d_ws;
    auto take = [&](size_t bytes) -> void* {
        void* r = base + o;
        o = (o + bytes + 255) & ~(size_t)255;
        return r;
    };
    int*   deg     = (int*)take(NN * 4);
    int*   cursor  = (int*)take(NN * 4);
    int*   row_ptr = (int*)take(50304 * 4);
    int*   sums    = (int*)take(64 * 4);
    int*   csr     = (int*)take(NE * 4);
    float* inv_deg = (float*)take(NN * 4);
    float* aggm    = (float*)take((size_t)NN * DD * 4);
    float* hA      = (float*)take((size_t)NN * DD * 4);
    float* hB      = (float*)take((size_t)NN * DD * 4);
    f16*   F0      = (f16*)take((size_t)NN * DD * 2);   // f16 shadow ping
    f16*   F1      = (f16*)take((size_t)NN * DD * 2);   // f16 shadow pong
    f16*   BTLh    = (f16*)take(98304 * 2);
    f16*   BTLl    = (f16*)take(98304 * 2);
    f16*   BT1h    = (f16*)take(16384 * 2);
    f16*   BT1l    = (f16*)take(16384 * 2);
    f16*   BT2h    = (f16*)take(16384 * 2);
    f16*   BT2l    = (f16*)take(16384 * 2);
    (void)ws_size; (void)n_in; (void)in_sizes; (void)out_size;

    hipMemsetAsync(deg, 0, NN * 4, stream);
    hipMemsetAsync(cursor, 0, NN * 4, stream);

    k_prep<<<512, 256, 0, stream>>>(W_self, W_neigh, Wp1, Wp2, BTLh, BTLl, BT1h, BT1l, BT2h, BT2l);
    k_cast<<<(NN * DD / 4 + 255) / 256, 256, 0, stream>>>(x, F0);

    k_count<<<(NE + 255) / 256, 256, 0, stream>>>(edge_dst, deg);
    k_scan1<<<49, 1024, 0, stream>>>(deg, row_ptr, sums);
    k_scan2<<<1, 64, 0, stream>>>(sums);
    k_scan3<<<(NN + 255) / 256, 256, 0, stream>>>(row_ptr, sums, deg, inv_deg);
    k_fill<<<(NE + 255) / 256, 256, 0, stream>>>(edge_src, edge_dst, row_ptr, cursor, csr);

    const int aggGrid = (NN + 3) / 4;
    const int layGrid = (NN + 127) / 128;

    // layer 0: x -> hA (+F1)
    k_agg16<<<aggGrid, 256, 0, stream>>>(F0, row_ptr, csr, inv_deg, aggm);
    k_layer<1, 1><<<layGrid, 256, 0, stream>>>(x, aggm, BTLh, BTLl, b, hA, F1);
    // layer 1: hA -> hB (+F0)
    k_agg16<<<aggGrid, 256, 0, stream>>>(F1, row_ptr, csr, inv_deg, aggm);
    k_layer<1, 1><<<layGrid, 256, 0, stream>>>(hA, aggm, BTLh + 32768, BTLl + 32768, b + 128, hB, F0);
    // layer 2 (no relu): hB -> hA
    k_agg16<<<aggGrid, 256, 0, stream>>>(F0, row_ptr, csr, inv_deg, aggm);
    k_layer<0, 0><<<layGrid, 256, 0, stream>>>(hB, aggm, BTLh + 65536, BTLl + 65536, b + 256, hA, F1);

    k_pred<<<(2 * NP + 127) / 128, 256, 0, stream>>>(hA, pos_src, pos_dst, neg_src, neg_dst,
                                                     BT1h, BT1l, BT2h, BT2l,
                                                     bp1, bp2, Wp3, bp3, out);
}

// Round 10
// 395.733 us; speedup vs baseline: 2.5273x; 1.0208x over previous
//
#include <hip/hip_runtime.h>

#define NN 50000
#define NE 600000
#define NP 100000
#define DD 128

typedef _Float16 f16;
typedef _Float16 f16x4 __attribute__((ext_vector_type(4)));
typedef _Float16 f16x8 __attribute__((ext_vector_type(8)));
typedef float f32x4v __attribute__((ext_vector_type(4)));

// ---------------- CSR build ----------------

__global__ __launch_bounds__(256) void k_count(const int* __restrict__ dst, int* __restrict__ deg) {
    int i = blockIdx.x * 256 + threadIdx.x;
    if (i < NE) atomicAdd(&deg[dst[i]], 1);
}

__global__ __launch_bounds__(1024) void k_scan1(const int* __restrict__ deg, int* __restrict__ excl,
                                                int* __restrict__ sums) {
    __shared__ int tmp[1024];
    int t = threadIdx.x;
    int gid = blockIdx.x * 1024 + t;
    int v = (gid < NN) ? deg[gid] : 0;
    tmp[t] = v;
    __syncthreads();
    #pragma unroll
    for (int off = 1; off < 1024; off <<= 1) {
        int u = (t >= off) ? tmp[t - off] : 0;
        __syncthreads();
        tmp[t] += u;
        __syncthreads();
    }
    excl[gid] = tmp[t] - v;
    if (t == 1023) sums[blockIdx.x] = tmp[t];
}

__global__ __launch_bounds__(64) void k_scan2(int* __restrict__ sums) {
    int t = threadIdx.x;
    int v = (t < 49) ? sums[t] : 0;
    int orig = v;
    #pragma unroll
    for (int off = 1; off < 64; off <<= 1) {
        int u = __shfl_up(v, off, 64);
        if (t >= off) v += u;
    }
    if (t < 64) sums[t] = v - orig;
}

__global__ __launch_bounds__(256) void k_scan3(int* __restrict__ row_ptr, const int* __restrict__ sums,
                                               const int* __restrict__ deg, float* __restrict__ inv_deg) {
    int i = blockIdx.x * 256 + threadIdx.x;
    if (i < NN) {
        row_ptr[i] += sums[i >> 10];
        int d = deg[i];
        inv_deg[i] = 1.0f / (float)(d > 1 ? d : 1);
        if (i == 0) row_ptr[NN] = NE;
    }
}

__global__ __launch_bounds__(256) void k_fill(const int* __restrict__ src, const int* __restrict__ dst,
                                              const int* __restrict__ row_ptr, int* __restrict__ cursor,
                                              int* __restrict__ csr) {
    int i = blockIdx.x * 256 + threadIdx.x;
    if (i < NE) {
        int d = dst[i];
        int p = row_ptr[d] + atomicAdd(&cursor[d], 1);
        csr[p] = src[i];
    }
}

// ---------------- cast x -> f16 shadow ----------------

__global__ __launch_bounds__(256) void k_cast(const float* __restrict__ x, f16* __restrict__ x16) {
    int i = blockIdx.x * 256 + threadIdx.x;
    float4 v = ((const float4*)x)[i];
    f16x4 o;
    o[0] = (f16)v.x; o[1] = (f16)v.y; o[2] = (f16)v.z; o[3] = (f16)v.w;
    *(f16x4*)(x16 + 4 * (size_t)i) = o;
}

// ---------------- mean aggregation from f16 rows: one wave per node ----------------

__global__ __launch_bounds__(256) void k_agg16(const f16* __restrict__ h16, const int* __restrict__ row_ptr,
                                               const int* __restrict__ csr, const float* __restrict__ inv_deg,
                                               float* __restrict__ agg) {
    int wid = (int)((blockIdx.x * 256 + threadIdx.x) >> 6);
    int lane = threadIdx.x & 63;
    if (wid >= NN) return;
    int beg = row_ptr[wid], end = row_ptr[wid + 1];
    int grp = lane >> 4, sl = lane & 15;
    float acc[8] = {0.f, 0.f, 0.f, 0.f, 0.f, 0.f, 0.f, 0.f};
    int i = beg;
    for (; i + 8 <= end; i += 8) {
        int s0 = csr[i + grp], s1 = csr[i + 4 + grp];
        f16x8 v0 = *(const f16x8*)(h16 + (size_t)s0 * DD + 8 * sl);
        f16x8 v1 = *(const f16x8*)(h16 + (size_t)s1 * DD + 8 * sl);
        #pragma unroll
        for (int q = 0; q < 8; ++q) acc[q] += (float)v0[q] + (float)v1[q];
    }
    for (; i + grp < end; i += 4) {
        int s0 = csr[i + grp];
        f16x8 v = *(const f16x8*)(h16 + (size_t)s0 * DD + 8 * sl);
        #pragma unroll
        for (int q = 0; q < 8; ++q) acc[q] += (float)v[q];
    }
    #pragma unroll
    for (int q = 0; q < 8; ++q) {
        acc[q] += __shfl_xor(acc[q], 16, 64);
        acc[q] += __shfl_xor(acc[q], 32, 64);
    }
    if (grp == 0) {
        float sc = inv_deg[wid];
        float4 o0 = {acc[0] * sc, acc[1] * sc, acc[2] * sc, acc[3] * sc};
        float4 o1 = {acc[4] * sc, acc[5] * sc, acc[6] * sc, acc[7] * sc};
        float4* dst = (float4*)(agg + (size_t)wid * DD + 8 * sl);
        dst[0] = o0; dst[1] = o1;
    }
}

// ---------------- weight prep: split fp32 -> f16 hi/lo, transposed [n][k] ----------------

__global__ __launch_bounds__(256) void k_prep(const float* __restrict__ Wsf, const float* __restrict__ Wng,
                                              const float* __restrict__ Wp1, const float* __restrict__ Wp2,
                                              f16* __restrict__ BTLh, f16* __restrict__ BTLl,
                                              f16* __restrict__ BT1h, f16* __restrict__ BT1l,
                                              f16* __restrict__ BT2h, f16* __restrict__ BT2l) {
    int idx = blockIdx.x * 256 + threadIdx.x;
    float wv;
    f16 *dh, *dl;
    int off;
    if (idx < 98304) {
        int l = idx >> 15;
        int rem = idx & 32767;
        int n = rem >> 8;
        int k = rem & 255;
        wv = (k < 128) ? Wsf[l * 16384 + k * 128 + n] : Wng[l * 16384 + (k - 128) * 128 + n];
        dh = BTLh; dl = BTLl; off = idx;
    } else if (idx < 114688) {
        int p = idx - 98304;
        int n = p >> 7, k = p & 127;
        wv = Wp1[k * 128 + n];
        dh = BT1h; dl = BT1l; off = p;
    } else {
        int p = idx - 114688;
        int n = p >> 7, k = p & 127;
        wv = Wp2[k * 128 + n];
        dh = BT2h; dl = BT2l; off = p;
    }
    f16 hi = (f16)wv;
    dh[off] = hi;
    dl[off] = (f16)(wv - (float)hi);
}

// ---------------- SAGE layer via MFMA ----------------

template <int RELU, int W16>
__global__ __launch_bounds__(256) void k_layer(const float* __restrict__ hin, const float* __restrict__ agg,
                                               const f16* __restrict__ BTh, const f16* __restrict__ BTl,
                                               const float* __restrict__ bias, float* __restrict__ hout,
                                               f16* __restrict__ hout16) {
    __shared__ __align__(16) f16 Ah[128][40];
    __shared__ __align__(16) f16 Al[128][40];
    __shared__ __align__(16) f16 Bh[128][40];
    __shared__ __align__(16) f16 Bl[128][40];
    int t = threadIdx.x;
    int lane = t & 63;
    int w = t >> 6;
    int lo16 = lane & 15;
    int kg = lane >> 4;
    int row0 = blockIdx.x * 128;
    f32x4v acc[2][8];
    #pragma unroll
    for (int m = 0; m < 2; ++m)
        #pragma unroll
        for (int n = 0; n < 8; ++n) acc[m][n] = (f32x4v){0.f, 0.f, 0.f, 0.f};

    #pragma unroll 1
    for (int kc = 0; kc < 8; ++kc) {
        __syncthreads();
        {   // stage A chunk: 128 rows x 32 k fp32 -> hi/lo f16
            const float* src = (kc < 4) ? hin : agg;
            int kb = (kc & 3) * 8;
            #pragma unroll
            for (int p = 0; p < 4; ++p) {
                int i = t + p * 256;
                int r = i >> 3, q = i & 7;
                float4 v = {0.f, 0.f, 0.f, 0.f};
                int gr = row0 + r;
                if (gr < NN) v = ((const float4*)src)[(size_t)gr * 32 + kb + q];
                f16x4 vh, vl;
                vh[0] = (f16)v.x; vl[0] = (f16)(v.x - (float)vh[0]);
                vh[1] = (f16)v.y; vl[1] = (f16)(v.y - (float)vh[1]);
                vh[2] = (f16)v.z; vl[2] = (f16)(v.z - (float)vh[2]);
                vh[3] = (f16)v.w; vl[3] = (f16)(v.w - (float)vh[3]);
                *(f16x4*)&Ah[r][4 * q] = vh;
                *(f16x4*)&Al[r][4 * q] = vl;
            }
        }
        {   // stage B chunk: pre-split BT[n][k] slices
            #pragma unroll
            for (int p = 0; p < 2; ++p) {
                int i = t + p * 256;
                int n = i >> 2, j = i & 3;
                *(uint4*)&Bh[n][8 * j] = *(const uint4*)&BTh[n * 256 + kc * 32 + 8 * j];
                *(uint4*)&Bl[n][8 * j] = *(const uint4*)&BTl[n * 256 + kc * 32 + 8 * j];
            }
        }
        __syncthreads();
        f16x8 ah[2], al[2];
        #pragma unroll
        for (int m = 0; m < 2; ++m) {
            ah[m] = *(const f16x8*)&Ah[w * 32 + m * 16 + lo16][8 * kg];
            al[m] = *(const f16x8*)&Al[w * 32 + m * 16 + lo16][8 * kg];
        }
        #pragma unroll
        for (int n = 0; n < 8; ++n) {
            f16x8 bh = *(const f16x8*)&Bh[16 * n + lo16][8 * kg];
            f16x8 bl = *(const f16x8*)&Bl[16 * n + lo16][8 * kg];
            #pragma unroll
            for (int m = 0; m < 2; ++m) {
                acc[m][n] = __builtin_amdgcn_mfma_f32_16x16x32_f16(ah[m], bh, acc[m][n], 0, 0, 0);
                acc[m][n] = __builtin_amdgcn_mfma_f32_16x16x32_f16(al[m], bh, acc[m][n], 0, 0, 0);
                acc[m][n] = __builtin_amdgcn_mfma_f32_16x16x32_f16(ah[m], bl, acc[m][n], 0, 0, 0);
            }
        }
    }
    // epilogue
    #pragma unroll
    for (int m = 0; m < 2; ++m)
        #pragma unroll
        for (int r = 0; r < 4; ++r) {
            int row = row0 + w * 32 + m * 16 + kg * 4 + r;
            if (row < NN) {
                #pragma unroll
                for (int n = 0; n < 8; ++n) {
                    int col = 16 * n + lo16;
                    float v = acc[m][n][r] + bias[col];
                    if (RELU) v = fmaxf(v, 0.f);
                    hout[(size_t)row * 128 + col] = v;
                    if (W16) hout16[(size_t)row * 128 + col] = (f16)v;
                }
            }
        }
}

// ---------------- fused predictor via MFMA: e gathered from f16 shadow ----------------

__global__ __launch_bounds__(256) void k_pred(const f16* __restrict__ h16,
                                              const int* __restrict__ ps, const int* __restrict__ pd,
                                              const int* __restrict__ ns, const int* __restrict__ nd,
                                              const f16* __restrict__ BT1h, const f16* __restrict__ BT1l,
                                              const f16* __restrict__ BT2h, const f16* __restrict__ BT2l,
                                              const float* __restrict__ bp1, const float* __restrict__ bp2,
                                              const float* __restrict__ Wp3, const float* __restrict__ bp3,
                                              float* __restrict__ out) {
    __shared__ __align__(16) f16 Z2[128][72];
    __shared__ __align__(16) f16 Bh[128][40];
    __shared__ __align__(16) f16 Bl[128][40];
    int t = threadIdx.x;
    int lane = t & 63;
    int w = t >> 6;
    int lo16 = lane & 15;
    int kg = lane >> 4;
    int row0 = blockIdx.x * 128;
    int sIdx[2], dIdx[2];
    #pragma unroll
    for (int m = 0; m < 2; ++m) {
        int row = row0 + w * 32 + m * 16 + lo16;
        int s = 0, d = 0;
        if (row < NP)           { s = ps[row];      d = pd[row]; }
        else if (row < 2 * NP)  { s = ns[row - NP]; d = nd[row - NP]; }
        sIdx[m] = s; dIdx[m] = d;
    }
    f32x4v acc[2][8];
    #pragma unroll
    for (int m = 0; m < 2; ++m)
        #pragma unroll
        for (int n = 0; n < 8; ++n) acc[m][n] = (f32x4v){0.f, 0.f, 0.f, 0.f};

    // ---- GEMM1: acc = e @ Wp1 (3-term); e from f16 rows (exact product in fp32) ----
    #pragma unroll 1
    for (int kc = 0; kc < 4; ++kc) {
        __syncthreads();
        #pragma unroll
        for (int p = 0; p < 2; ++p) {
            int i = t + p * 256;
            int n = i >> 2, j = i & 3;
            *(uint4*)&Bh[n][8 * j] = *(const uint4*)&BT1h[n * 128 + kc * 32 + 8 * j];
            *(uint4*)&Bl[n][8 * j] = *(const uint4*)&BT1l[n * 128 + kc * 32 + 8 * j];
        }
        __syncthreads();
        f16x8 eh[2], el[2];
        #pragma unroll
        for (int m = 0; m < 2; ++m) {
            int koff = kc * 32 + kg * 8;
            f16x8 a = *(const f16x8*)(h16 + (size_t)sIdx[m] * DD + koff);
            f16x8 b = *(const f16x8*)(h16 + (size_t)dIdx[m] * DD + koff);
            #pragma unroll
            for (int q = 0; q < 8; ++q) {
                float e = (float)a[q] * (float)b[q];
                f16 hi = (f16)e;
                eh[m][q] = hi;
                el[m][q] = (f16)(e - (float)hi);
            }
        }
        #pragma unroll
        for (int n = 0; n < 8; ++n) {
            f16x8 bh = *(const f16x8*)&Bh[16 * n + lo16][8 * kg];
            f16x8 bl = *(const f16x8*)&Bl[16 * n + lo16][8 * kg];
            #pragma unroll
            for (int m = 0; m < 2; ++m) {
                acc[m][n] = __builtin_amdgcn_mfma_f32_16x16x32_f16(eh[m], bh, acc[m][n], 0, 0, 0);
                acc[m][n] = __builtin_amdgcn_mfma_f32_16x16x32_f16(el[m], bh, acc[m][n], 0, 0, 0);
                acc[m][n] = __builtin_amdgcn_mfma_f32_16x16x32_f16(eh[m], bl, acc[m][n], 0, 0, 0);
            }
        }
    }
    // z1 half B (cols 64..127) parked in registers as f16
    f16x4 zb[2][4];
    #pragma unroll
    for (int m = 0; m < 2; ++m)
        #pragma unroll
        for (int n = 0; n < 4; ++n) {
            float bv = bp1[16 * (n + 4) + lo16];
            #pragma unroll
            for (int r = 0; r < 4; ++r)
                zb[m][n][r] = (f16)fmaxf(acc[m][n + 4][r] + bv, 0.f);
        }

    // ---- GEMM2: acc2 = z1 @ Wp2 (2-term), Z2 holds 64 cols at a time ----
    f32x4v acc2[2][8];
    #pragma unroll
    for (int m = 0; m < 2; ++m)
        #pragma unroll
        for (int n = 0; n < 8; ++n) acc2[m][n] = (f32x4v){0.f, 0.f, 0.f, 0.f};
    #pragma unroll 1
    for (int kc = 0; kc < 4; ++kc) {
        __syncthreads();
        if (kc == 0) {
            #pragma unroll
            for (int m = 0; m < 2; ++m)
                #pragma unroll
                for (int n = 0; n < 4; ++n) {
                    int col = 16 * n + lo16;
                    float bv = bp1[col];
                    #pragma unroll
                    for (int r = 0; r < 4; ++r)
                        Z2[w * 32 + m * 16 + kg * 4 + r][col] = (f16)fmaxf(acc[m][n][r] + bv, 0.f);
                }
        }
        if (kc == 2) {
            #pragma unroll
            for (int m = 0; m < 2; ++m)
                #pragma unroll
                for (int n = 0; n < 4; ++n)
                    #pragma unroll
                    for (int r = 0; r < 4; ++r)
                        Z2[w * 32 + m * 16 + kg * 4 + r][16 * n + lo16] = zb[m][n][r];
        }
        #pragma unroll
        for (int p = 0; p < 2; ++p) {
            int i = t + p * 256;
            int n = i >> 2, j = i & 3;
            *(uint4*)&Bh[n][8 * j] = *(const uint4*)&BT2h[n * 128 + kc * 32 + 8 * j];
            *(uint4*)&Bl[n][8 * j] = *(const uint4*)&BT2l[n * 128 + kc * 32 + 8 * j];
        }
        __syncthreads();
        f16x8 zf[2];
        #pragma unroll
        for (int m = 0; m < 2; ++m)
            zf[m] = *(const f16x8*)&Z2[w * 32 + m * 16 + lo16][(kc & 1) * 32 + 8 * kg];
        #pragma unroll
        for (int n = 0; n < 8; ++n) {
            f16x8 bh = *(const f16x8*)&Bh[16 * n + lo16][8 * kg];
            f16x8 bl = *(const f16x8*)&Bl[16 * n + lo16][8 * kg];
            #pragma unroll
            for (int m = 0; m < 2; ++m) {
                acc2[m][n] = __builtin_amdgcn_mfma_f32_16x16x32_f16(zf[m], bh, acc2[m][n], 0, 0, 0);
                acc2[m][n] = __builtin_amdgcn_mfma_f32_16x16x32_f16(zf[m], bl, acc2[m][n], 0, 0, 0);
            }
        }
    }
    // epilogue: p = sum_col relu(acc2 + bp2) * Wp3, reduce over the 16 col-lanes
    float p[2][4] = {{0.f, 0.f, 0.f, 0.f}, {0.f, 0.f, 0.f, 0.f}};
    #pragma unroll
    for (int m = 0; m < 2; ++m)
        #pragma unroll
        for (int n = 0; n < 8; ++n) {
            int col = 16 * n + lo16;
            float bv = bp2[col], w3 = Wp3[col];
            #pragma unroll
            for (int r = 0; r < 4; ++r)
                p[m][r] = fmaf(fmaxf(acc2[m][n][r] + bv, 0.f), w3, p[m][r]);
        }
    #pragma unroll
    for (int off = 1; off < 16; off <<= 1) {
        #pragma unroll
        for (int m = 0; m < 2; ++m)
            #pragma unroll
            for (int r = 0; r < 4; ++r)
                p[m][r] += __shfl_xor(p[m][r], off, 64);
    }
    if (lo16 == 0) {
        float bb = bp3[0];
        #pragma unroll
        for (int m = 0; m < 2; ++m)
            #pragma unroll
            for (int r = 0; r < 4; ++r) {
                int row = row0 + w * 32 + m * 16 + kg * 4 + r;
                if (row < 2 * NP) out[row] = p[m][r] + bb;
            }
    }
}

// ---------------- launch ----------------

extern "C" void kernel_launch(void* const* d_in, const int* in_sizes, int n_in,
                              void* d_out, int out_size, void* d_ws, size_t ws_size,
                              hipStream_t stream) {
    const float* x      = (const float*)d_in[0];
    const float* W_self = (const float*)d_in[1];
    const float* W_neigh= (const float*)d_in[2];
    const float* b      = (const float*)d_in[3];
    const float* Wp1    = (const float*)d_in[4];
    const float* bp1    = (const float*)d_in[5];
    const float* Wp2    = (const float*)d_in[6];
    const float* bp2    = (const float*)d_in[7];
    const float* Wp3    = (const float*)d_in[8];
    const float* bp3    = (const float*)d_in[9];
    const int* edge_src = (const int*)d_in[10];
    const int* edge_dst = (const int*)d_in[11];
    const int* pos_src  = (const int*)d_in[12];
    const int* pos_dst  = (const int*)d_in[13];
    const int* neg_src  = (const int*)d_in[14];
    const int* neg_dst  = (const int*)d_in[15];
    float* out = (float*)d_out;

    size_t o = 0;
    char* base = (char*)d_ws;
    auto take = [&](size_t bytes) -> void* {
        void* r = base + o;
        o = (o + bytes + 255) & ~(size_t)255;
        return r;
    };
    int*   deg     = (int*)take(NN * 4);
    int*   cursor  = (int*)take(NN * 4);
    int*   row_ptr = (int*)take(50304 * 4);
    int*   sums    = (int*)take(64 * 4);
    int*   csr     = (int*)take(NE * 4);
    float* inv_deg = (float*)take(NN * 4);
    float* aggm    = (float*)take((size_t)NN * DD * 4);
    float* hA      = (float*)take((size_t)NN * DD * 4);
    float* hB      = (float*)take((size_t)NN * DD * 4);
    f16*   F0      = (f16*)take((size_t)NN * DD * 2);
    f16*   F1      = (f16*)take((size_t)NN * DD * 2);
    f16*   BTLh    = (f16*)take(98304 * 2);
    f16*   BTLl    = (f16*)take(98304 * 2);
    f16*   BT1h    = (f16*)take(16384 * 2);
    f16*   BT1l    = (f16*)take(16384 * 2);
    f16*   BT2h    = (f16*)take(16384 * 2);
    f16*   BT2l    = (f16*)take(16384 * 2);
    (void)ws_size; (void)n_in; (void)in_sizes; (void)out_size;

    hipMemsetAsync(deg, 0, NN * 4, stream);
    hipMemsetAsync(cursor, 0, NN * 4, stream);

    k_prep<<<512, 256, 0, stream>>>(W_self, W_neigh, Wp1, Wp2, BTLh, BTLl, BT1h, BT1l, BT2h, BT2l);
    k_cast<<<(NN * DD / 4 + 255) / 256, 256, 0, stream>>>(x, F0);

    k_count<<<(NE + 255) / 256, 256, 0, stream>>>(edge_dst, deg);
    k_scan1<<<49, 1024, 0, stream>>>(deg, row_ptr, sums);
    k_scan2<<<1, 64, 0, stream>>>(sums);
    k_scan3<<<(NN + 255) / 256, 256, 0, stream>>>(row_ptr, sums, deg, inv_deg);
    k_fill<<<(NE + 255) / 256, 256, 0, stream>>>(edge_src, edge_dst, row_ptr, cursor, csr);

    const int aggGrid = (NN + 3) / 4;
    const int layGrid = (NN + 127) / 128;

    // layer 0: x -> hA (+F1)
    k_agg16<<<aggGrid, 256, 0, stream>>>(F0, row_ptr, csr, inv_deg, aggm);
    k_layer<1, 1><<<layGrid, 256, 0, stream>>>(x, aggm, BTLh, BTLl, b, hA, F1);
    // layer 1: hA -> hB (+F0)
    k_agg16<<<aggGrid, 256, 0, stream>>>(F1, row_ptr, csr, inv_deg, aggm);
    k_layer<1, 1><<<layGrid, 256, 0, stream>>>(hA, aggm, BTLh + 32768, BTLl + 32768, b + 128, hB, F0);
    // layer 2 (no relu): hB -> hA (+F1 = f16(h3) for the predictor gather)
    k_agg16<<<aggGrid, 256, 0, stream>>>(F0, row_ptr, csr, inv_deg, aggm);
    k_layer<0, 1><<<layGrid, 256, 0, stream>>>(hB, aggm, BTLh + 65536, BTLl + 65536, b + 256, hA, F1);

    k_pred<<<(2 * NP + 127) / 128, 256, 0, stream>>>(F1, pos_src, pos_dst, neg_src, neg_dst,
                                                     BT1h, BT1l, BT2h, BT2l,
                                                     bp1, bp2, Wp3, bp3, out);
}